// Round 1
// baseline (84333.722 us; speedup 1.0000x reference)
//
#include <hip/hip_runtime.h>
#include <cstdint>
#include <cstddef>

// Problem constants (fixed by the reference).
constexpr int T_STEPS = 200;
constexpr int BATCH   = 2048;
constexpr int E_DIM   = 256;
constexpr int H_DIM   = 512;
constexpr int P0_DIM  = 256;
constexpr int P1_DIM  = 128;
constexpr float ALPHA = 0.3f;   // leaky relu slope

__device__ __forceinline__ float sigmoidf_(float x) { return 1.0f / (1.0f + expf(-x)); }

// ---------------------------------------------------------------------------
// Gates GEMM:  out[z] = act_z( A1@W1[z] + A2@W2[z] + bias[z] ),  z = 0..3
//   act: sigmoid for z<3 (f,i,o), tanh for z==3 (g)
//   A1: [B x K1] (x_t, lda1=E), A2: [B x K2] (H_c, lda2=H)
//   W1[z]: [K1 x H], W2[z]: [K2 x H] row-major, out: [4][B][H]
// Tile: BM=64, BN=128, BK=16; 256 threads; 4x8 per thread.
// ---------------------------------------------------------------------------
__global__ __launch_bounds__(256) void k_gates(
    const float* __restrict__ A1, int lda1, const float* __restrict__ W1, int K1,
    const float* __restrict__ A2, int lda2, const float* __restrict__ W2, int K2,
    const float* __restrict__ bias, float* __restrict__ out)
{
    const int z = blockIdx.z;
    const float* w1 = W1 + (size_t)z * K1 * H_DIM;
    const float* w2 = W2 + (size_t)z * K2 * H_DIM;
    const float* bz = bias + (size_t)z * H_DIM;
    float* oz = out + (size_t)z * BATCH * H_DIM;

    __shared__ float As[16][68];    // A-tile transposed: As[k][row]
    __shared__ float Bs[16][132];   // B-tile: Bs[k][col]

    const int tid = threadIdx.x;
    const int tx = tid & 15, ty = tid >> 4;
    const int brow = blockIdx.y * 64, bcol = blockIdx.x * 128;

    float acc[4][8];
#pragma unroll
    for (int i = 0; i < 4; ++i)
#pragma unroll
        for (int j = 0; j < 8; ++j) acc[i][j] = 0.0f;

    const int ar = tid >> 2, ak = (tid & 3) << 2;   // A stage: 64 rows x 16 k
    const int bk = tid >> 5, bc = (tid & 31) << 2;  // B stage: 8 k-rows/pass x 128 cols

    for (int seg = 0; seg < 2; ++seg) {
        const float* A   = seg ? A2   : A1;
        const float* W   = seg ? w2   : w1;
        const int    lda = seg ? lda2 : lda1;
        const int    K   = seg ? K2   : K1;
        const float* arow = A + (size_t)(brow + ar) * lda + ak;
        for (int k0 = 0; k0 < K; k0 += 16) {
            __syncthreads();
            float4 av = *(const float4*)(arow + k0);
            As[ak + 0][ar] = av.x; As[ak + 1][ar] = av.y;
            As[ak + 2][ar] = av.z; As[ak + 3][ar] = av.w;
#pragma unroll
            for (int p = 0; p < 2; ++p) {
                *(float4*)&Bs[p * 8 + bk][bc] =
                    *(const float4*)(W + (size_t)(k0 + p * 8 + bk) * H_DIM + bcol + bc);
            }
            __syncthreads();
#pragma unroll
            for (int kk = 0; kk < 16; ++kk) {
                float a[4], b[8];
                *(float4*)&a[0] = *(const float4*)&As[kk][ty * 4];
                *(float4*)&b[0] = *(const float4*)&Bs[kk][tx * 4];
                *(float4*)&b[4] = *(const float4*)&Bs[kk][64 + tx * 4];
#pragma unroll
                for (int i = 0; i < 4; ++i)
#pragma unroll
                    for (int j = 0; j < 8; ++j)
                        acc[i][j] = fmaf(a[i], b[j], acc[i][j]);
            }
        }
    }

#pragma unroll
    for (int i = 0; i < 4; ++i) {
        const int r = brow + ty * 4 + i;
#pragma unroll
        for (int jh = 0; jh < 2; ++jh) {
            const int c = bcol + jh * 64 + tx * 4;
            float4 v;
            v.x = acc[i][jh * 4 + 0] + bz[c + 0];
            v.y = acc[i][jh * 4 + 1] + bz[c + 1];
            v.z = acc[i][jh * 4 + 2] + bz[c + 2];
            v.w = acc[i][jh * 4 + 3] + bz[c + 3];
            if (z < 3) {
                v.x = sigmoidf_(v.x); v.y = sigmoidf_(v.y);
                v.z = sigmoidf_(v.z); v.w = sigmoidf_(v.w);
            } else {
                v.x = tanhf(v.x); v.y = tanhf(v.y);
                v.z = tanhf(v.z); v.w = tanhf(v.w);
            }
            *(float4*)(oz + (size_t)r * H_DIM + c) = v;
        }
    }
}

// ---------------------------------------------------------------------------
// Combine GEMM: two H_DIM-K products kept in separate accumulators, fused
// per-row-g epilogue:
//   mode 0 (click):  out = tanh((1-g)*(A1@W1) + g*(A2@W2))
//   mode 1 (conv):   out = tanh((A1@W1) + g*(A2@W2))
// Tile: 64x64, BK=16, 256 threads, 4x4 per thread, two acc sets.
// ---------------------------------------------------------------------------
__global__ __launch_bounds__(256) void k_combine(
    const float* __restrict__ A1, const float* __restrict__ W1,
    const float* __restrict__ A2, const float* __restrict__ W2,
    const float* __restrict__ g, float* __restrict__ out, int mode)
{
    __shared__ float As[16][68];
    __shared__ float Bs[16][68];
    const int tid = threadIdx.x;
    const int tx = tid & 15, ty = tid >> 4;
    const int brow = blockIdx.y * 64, bcol = blockIdx.x * 64;
    const int ar = tid >> 2, ak = (tid & 3) << 2;
    const int bk = tid >> 4, bc = (tid & 15) << 2;

    float acc1[4][4], acc2[4][4];
#pragma unroll
    for (int i = 0; i < 4; ++i)
#pragma unroll
        for (int j = 0; j < 4; ++j) { acc1[i][j] = 0.0f; acc2[i][j] = 0.0f; }

    // segment 1 -> acc1
    {
        const float* arow = A1 + (size_t)(brow + ar) * H_DIM + ak;
        for (int k0 = 0; k0 < H_DIM; k0 += 16) {
            __syncthreads();
            float4 av = *(const float4*)(arow + k0);
            As[ak + 0][ar] = av.x; As[ak + 1][ar] = av.y;
            As[ak + 2][ar] = av.z; As[ak + 3][ar] = av.w;
            *(float4*)&Bs[bk][bc] = *(const float4*)(W1 + (size_t)(k0 + bk) * H_DIM + bcol + bc);
            __syncthreads();
#pragma unroll
            for (int kk = 0; kk < 16; ++kk) {
                float a[4], b[4];
                *(float4*)&a[0] = *(const float4*)&As[kk][ty * 4];
                *(float4*)&b[0] = *(const float4*)&Bs[kk][tx * 4];
#pragma unroll
                for (int i = 0; i < 4; ++i)
#pragma unroll
                    for (int j = 0; j < 4; ++j)
                        acc1[i][j] = fmaf(a[i], b[j], acc1[i][j]);
            }
        }
    }
    // segment 2 -> acc2
    {
        const float* arow = A2 + (size_t)(brow + ar) * H_DIM + ak;
        for (int k0 = 0; k0 < H_DIM; k0 += 16) {
            __syncthreads();
            float4 av = *(const float4*)(arow + k0);
            As[ak + 0][ar] = av.x; As[ak + 1][ar] = av.y;
            As[ak + 2][ar] = av.z; As[ak + 3][ar] = av.w;
            *(float4*)&Bs[bk][bc] = *(const float4*)(W2 + (size_t)(k0 + bk) * H_DIM + bcol + bc);
            __syncthreads();
#pragma unroll
            for (int kk = 0; kk < 16; ++kk) {
                float a[4], b[4];
                *(float4*)&a[0] = *(const float4*)&As[kk][ty * 4];
                *(float4*)&b[0] = *(const float4*)&Bs[kk][tx * 4];
#pragma unroll
                for (int i = 0; i < 4; ++i)
#pragma unroll
                    for (int j = 0; j < 4; ++j)
                        acc2[i][j] = fmaf(a[i], b[j], acc2[i][j]);
            }
        }
    }

#pragma unroll
    for (int i = 0; i < 4; ++i) {
        const int r = brow + ty * 4 + i;
        const float gv = g[r];
        const int c = bcol + tx * 4;
        float v[4];
#pragma unroll
        for (int j = 0; j < 4; ++j) {
            float pre = (mode == 0) ? ((1.0f - gv) * acc1[i][j] + gv * acc2[i][j])
                                    : (acc1[i][j] + gv * acc2[i][j]);
            v[j] = tanhf(pre);
        }
        *(float4*)(out + (size_t)r * H_DIM + c) = *(float4*)&v[0];
    }
}

// ---------------------------------------------------------------------------
// MLP GEMM: out = leaky_relu(A@W + bias), A:[B x K], W:[K x N], 64x64 tiles.
// ---------------------------------------------------------------------------
__global__ __launch_bounds__(256) void k_mlp(
    const float* __restrict__ A, const float* __restrict__ W,
    const float* __restrict__ bias, float* __restrict__ out, int K, int N)
{
    __shared__ float As[16][68];
    __shared__ float Bs[16][68];
    const int tid = threadIdx.x;
    const int tx = tid & 15, ty = tid >> 4;
    const int brow = blockIdx.y * 64, bcol = blockIdx.x * 64;
    const int ar = tid >> 2, ak = (tid & 3) << 2;
    const int bk = tid >> 4, bc = (tid & 15) << 2;

    float acc[4][4];
#pragma unroll
    for (int i = 0; i < 4; ++i)
#pragma unroll
        for (int j = 0; j < 4; ++j) acc[i][j] = 0.0f;

    const float* arow = A + (size_t)(brow + ar) * K + ak;
    for (int k0 = 0; k0 < K; k0 += 16) {
        __syncthreads();
        float4 av = *(const float4*)(arow + k0);
        As[ak + 0][ar] = av.x; As[ak + 1][ar] = av.y;
        As[ak + 2][ar] = av.z; As[ak + 3][ar] = av.w;
        *(float4*)&Bs[bk][bc] = *(const float4*)(W + (size_t)(k0 + bk) * N + bcol + bc);
        __syncthreads();
#pragma unroll
        for (int kk = 0; kk < 16; ++kk) {
            float a[4], b[4];
            *(float4*)&a[0] = *(const float4*)&As[kk][ty * 4];
            *(float4*)&b[0] = *(const float4*)&Bs[kk][tx * 4];
#pragma unroll
            for (int i = 0; i < 4; ++i)
#pragma unroll
                for (int j = 0; j < 4; ++j)
                    acc[i][j] = fmaf(a[i], b[j], acc[i][j]);
        }
    }

#pragma unroll
    for (int i = 0; i < 4; ++i) {
        const int r = brow + ty * 4 + i;
        const int c = bcol + tx * 4;
        float v[4];
#pragma unroll
        for (int j = 0; j < 4; ++j) {
            float x = acc[i][j] + bias[c + j];
            v[j] = (x > 0.0f) ? x : ALPHA * x;
        }
        *(float4*)(out + (size_t)r * N + c) = *(float4*)&v[0];
    }
}

// ---------------------------------------------------------------------------
// Head: val = sigmoid(dot(p1[row], Wf) + bf);  optional *gmul, write gstate/pred.
// ---------------------------------------------------------------------------
__global__ __launch_bounds__(256) void k_head(
    const float* __restrict__ p1, const float* __restrict__ Wf,
    const float* __restrict__ bf, float* gstate, const float* gmul, float* pred)
{
    const int row = blockIdx.x * 256 + threadIdx.x;
    if (row >= BATCH) return;
    float s = bf[0];
    const float* pr = p1 + (size_t)row * P1_DIM;
#pragma unroll 8
    for (int k = 0; k < P1_DIM; ++k) s = fmaf(pr[k], Wf[k], s);
    float val = sigmoidf_(s);
    if (gmul)   val *= gmul[row];
    if (gstate) gstate[row] = val;
    if (pred)   pred[row] = val;
}

// ---------------------------------------------------------------------------
// LSTM elementwise updates (gates already activated; shat already tanh'd/combined)
// click:  s_c = shat + i*g_c + (1-g)*(f*s_c);  H_c = o*tanh(s_c)     [g = prev g]
// conv:   s_v = shat + (1-g)*s_v + g*(f*s_v + i*g_v);
//         H_v = (1-g)*H_v + g*(o*tanh(s_v))                           [g = new g]
// ---------------------------------------------------------------------------
__global__ __launch_bounds__(256) void k_lstm_c(
    const float* __restrict__ gates, const float* __restrict__ shat,
    const float* __restrict__ g, float* __restrict__ s_c, float* __restrict__ H_c)
{
    const int idx = blockIdx.x * 256 + threadIdx.x;
    const int row = idx >> 9;   // / H_DIM
    const float f  = gates[idx];
    const float ii = gates[(size_t)BATCH * H_DIM + idx];
    const float o  = gates[(size_t)2 * BATCH * H_DIM + idx];
    const float gg = gates[(size_t)3 * BATCH * H_DIM + idx];
    const float gv = g[row];
    const float s = shat[idx] + ii * gg + (1.0f - gv) * (f * s_c[idx]);
    s_c[idx] = s;
    H_c[idx] = o * tanhf(s);
}

__global__ __launch_bounds__(256) void k_lstm_v(
    const float* __restrict__ gates, const float* __restrict__ shat,
    const float* __restrict__ g, float* __restrict__ s_v, float* __restrict__ H_v)
{
    const int idx = blockIdx.x * 256 + threadIdx.x;
    const int row = idx >> 9;
    const float f  = gates[idx];
    const float ii = gates[(size_t)BATCH * H_DIM + idx];
    const float o  = gates[(size_t)2 * BATCH * H_DIM + idx];
    const float gg = gates[(size_t)3 * BATCH * H_DIM + idx];
    const float gv = g[row];
    const float sv_old = s_v[idx];
    const float s = shat[idx] + (1.0f - gv) * sv_old + gv * (f * sv_old + ii * gg);
    s_v[idx] = s;
    H_v[idx] = (1.0f - gv) * H_v[idx] + gv * (o * tanhf(s));
}

__global__ __launch_bounds__(256) void k_zero4(
    float* __restrict__ a, float* __restrict__ b,
    float* __restrict__ c, float* __restrict__ d)
{
    const int i = blockIdx.x * 256 + threadIdx.x;
    a[i] = 0.0f; b[i] = 0.0f; c[i] = 0.0f; d[i] = 0.0f;
}

// ---------------------------------------------------------------------------
extern "C" void kernel_launch(void* const* d_in, const int* in_sizes, int n_in,
                              void* d_out, int out_size, void* d_ws, size_t ws_size,
                              hipStream_t stream)
{
    (void)in_sizes; (void)n_in; (void)out_size; (void)ws_size;

    const float* inputs = (const float*)d_in[0];
    const float* Wx_c   = (const float*)d_in[1];
    const float* bx_c   = (const float*)d_in[2];
    const float* Wh_c   = (const float*)d_in[3];
    const float* Wx_v   = (const float*)d_in[4];
    const float* bx_v   = (const float*)d_in[5];
    const float* Wh_v   = (const float*)d_in[6];
    const float* Ws     = (const float*)d_in[7];
    const float* Wpc0   = (const float*)d_in[8];
    const float* bpc0   = (const float*)d_in[9];
    const float* Wpc1   = (const float*)d_in[10];
    const float* bpc1   = (const float*)d_in[11];
    const float* Wfcc   = (const float*)d_in[12];
    const float* bfcc   = (const float*)d_in[13];
    const float* Wpv0   = (const float*)d_in[14];
    const float* bpv0   = (const float*)d_in[15];
    const float* Wpv1   = (const float*)d_in[16];
    const float* bpv1   = (const float*)d_in[17];
    const float* Wfcv   = (const float*)d_in[18];
    const float* bfcv   = (const float*)d_in[19];
    float* out = (float*)d_out;

    // workspace carve-out (all fp32), ~39 MB total
    char* ws = (char*)d_ws;
    size_t off = 0;
    auto alloc = [&](size_t nfloats) {
        float* p = (float*)(ws + off);
        off += nfloats * sizeof(float);
        off = (off + 255) & ~(size_t)255;
        return p;
    };
    float* H_c   = alloc((size_t)BATCH * H_DIM);
    float* H_v   = alloc((size_t)BATCH * H_DIM);
    float* s_c   = alloc((size_t)BATCH * H_DIM);
    float* s_v   = alloc((size_t)BATCH * H_DIM);
    float* g     = alloc(BATCH);
    float* gates = alloc((size_t)4 * BATCH * H_DIM);
    float* shat  = alloc((size_t)BATCH * H_DIM);
    float* p0    = alloc((size_t)BATCH * P0_DIM);
    float* p1    = alloc((size_t)BATCH * P1_DIM);

    const dim3 thr(256);
    const dim3 grid_gates(H_DIM / 128, BATCH / 64, 4);
    const dim3 grid_comb(H_DIM / 64, BATCH / 64);
    const dim3 grid_mlp0(P0_DIM / 64, BATCH / 64);
    const dim3 grid_mlp1(P1_DIM / 64, BATCH / 64);
    const int  grid_ew = BATCH * H_DIM / 256;

    // ---- init: zero state; g0 = predict_c(zeros) ----
    k_zero4<<<grid_ew, thr, 0, stream>>>(H_c, H_v, s_c, s_v);
    k_mlp<<<grid_mlp0, thr, 0, stream>>>(H_c, Wpc0, bpc0, p0, H_DIM, P0_DIM);
    k_mlp<<<grid_mlp1, thr, 0, stream>>>(p0, Wpc1, bpc1, p1, P0_DIM, P1_DIM);
    k_head<<<BATCH / 256, thr, 0, stream>>>(p1, Wfcc, bfcc, g, nullptr, nullptr);

    for (int t = 0; t < T_STEPS; ++t) {
        const float* xt = inputs + (size_t)t * BATCH * E_DIM;

        // ---- click stream ----
        k_gates<<<grid_gates, thr, 0, stream>>>(xt, E_DIM, Wx_c, E_DIM,
                                                H_c, H_DIM, Wh_c, H_DIM, bx_c, gates);
        k_combine<<<grid_comb, thr, 0, stream>>>(H_c, Ws + 0 * H_DIM * H_DIM,
                                                 H_v, Ws + 1 * H_DIM * H_DIM,
                                                 g, shat, 0);
        k_lstm_c<<<grid_ew, thr, 0, stream>>>(gates, shat, g, s_c, H_c);
        k_mlp<<<grid_mlp0, thr, 0, stream>>>(H_c, Wpc0, bpc0, p0, H_DIM, P0_DIM);
        k_mlp<<<grid_mlp1, thr, 0, stream>>>(p0, Wpc1, bpc1, p1, P0_DIM, P1_DIM);
        // writes g = H_c_p and pred_c[t]
        k_head<<<BATCH / 256, thr, 0, stream>>>(p1, Wfcc, bfcc, g, nullptr,
                                                out + (size_t)t * BATCH);

        // ---- conversion stream (uses updated H_c and updated g) ----
        k_gates<<<grid_gates, thr, 0, stream>>>(xt, E_DIM, Wx_v, E_DIM,
                                                H_c, H_DIM, Wh_v, H_DIM, bx_v, gates);
        k_combine<<<grid_comb, thr, 0, stream>>>(H_v, Ws + 2 * (size_t)H_DIM * H_DIM,
                                                 H_c, Ws + 3 * (size_t)H_DIM * H_DIM,
                                                 g, shat, 1);
        k_lstm_v<<<grid_ew, thr, 0, stream>>>(gates, shat, g, s_v, H_v);
        k_mlp<<<grid_mlp0, thr, 0, stream>>>(H_v, Wpv0, bpv0, p0, H_DIM, P0_DIM);
        k_mlp<<<grid_mlp1, thr, 0, stream>>>(p0, Wpv1, bpv1, p1, P0_DIM, P1_DIM);
        // writes pred_v[t] = sigmoid(.)*H_c_p  (g untouched)
        k_head<<<BATCH / 256, thr, 0, stream>>>(p1, Wfcv, bfcv, nullptr, g,
                                                out + (size_t)(T_STEPS + t) * BATCH);
    }
}

// Round 3
// 32022.928 us; speedup vs baseline: 2.6335x; 2.6335x over previous
//
#include <hip/hip_runtime.h>
#include <cstdint>
#include <cstddef>

constexpr int T_STEPS = 200;
constexpr int BATCH   = 2048;
constexpr int E_DIM   = 256;
constexpr int H_DIM   = 512;
constexpr int P0_DIM  = 256;
constexpr int P1_DIM  = 128;
constexpr float ALPHA = 0.3f;

typedef __attribute__((ext_vector_type(8))) short bf16x8;
typedef __attribute__((ext_vector_type(4))) float f32x4;

__device__ __forceinline__ float sigmoidf_(float x){ return 1.0f/(1.0f+expf(-x)); }

__device__ __forceinline__ unsigned short f2bf(float f){
    union { float f; unsigned u; } v; v.f = f;
    unsigned r = (v.u + 0x7FFFu + ((v.u >> 16) & 1u)) >> 16;   // RNE
    return (unsigned short)r;
}
__device__ __forceinline__ float bf2f(unsigned short h){
    union { unsigned u; float f; } v; v.u = ((unsigned)h) << 16; return v.f;
}
__device__ __forceinline__ void splitbf(float x, unsigned short& hi, unsigned short& lo){
    hi = f2bf(x);
    lo = f2bf(x - bf2f(hi));
}

#define GLOAD16(gp, lp) __builtin_amdgcn_global_load_lds( \
    (const __attribute__((address_space(1))) unsigned int*)(gp), \
    (__attribute__((address_space(3))) unsigned int*)(lp), 16, 0, 0)

// Stage a [ROWS][64] bf16 tile into linear LDS, slot-swizzled at the SOURCE
// (m173 pattern): LDS[r][s] holds global k-slot (s ^ (r&7)) of row r.
template<int ROWS>
__device__ __forceinline__ void stage64(const unsigned short* __restrict__ src, int ldk,
                                        char* ldsbase){
    constexpr int TOT = ROWS * 8;          // 16B slots
    const int tid = threadIdx.x;
#pragma unroll
    for (int i = 0; i < TOT/256; ++i){
        const int gsl = i*256 + tid;
        const int r = gsl >> 3, s = gsl & 7;
        const int ksrc = ((s ^ (r & 7)) << 3);
        GLOAD16(src + (size_t)r*ldk + ksrc, ldsbase + gsl*16);
    }
}

// Swizzled b128 fragment read: row-stride 128B (BK=64), kslot in [0,8).
__device__ __forceinline__ bf16x8 ldsfrag(const char* ldsbase, int row, int kslot){
    return *(const bf16x8*)(ldsbase + row*128 + ((kslot ^ (row & 7)) << 4));
}

// ---------------------------------------------------------------------------
// Fused gates GEMM, 3-term split precision:
//   out[z][b][h] = act( x@Wx[z] + H@Wh[z] + bias[z] )
// One GEMM: M=2048(b), N=2048(z*512+h), K=768. Each product computed as
// Ahi@Bhi + Alo@Bhi + Ahi@Blo. 128x128 tile, 4 waves 2x2.
// ---------------------------------------------------------------------------
__global__ __launch_bounds__(256) void k_gates(
    const unsigned short* __restrict__ Xhi, const unsigned short* __restrict__ Xlo,
    const unsigned short* __restrict__ Hhi, const unsigned short* __restrict__ Hlo,
    const unsigned short* __restrict__ WThi, const unsigned short* __restrict__ WTlo,
    const float* __restrict__ bias,           // [4][512]
    float* __restrict__ gates)                // [4][2048][512]
{
    __shared__ __align__(16) char lds[65536];
    char* ldsAhi = lds;
    char* ldsAlo = lds + 16384;
    char* ldsBhi = lds + 32768;
    char* ldsBlo = lds + 49152;
    const int tid = threadIdx.x;
    const int lane = tid & 63, wid = tid >> 6;
    const int wr = wid >> 1, wc = wid & 1;
    const int brow = blockIdx.y * 128, bcol = blockIdx.x * 128;
    const int lr = lane & 15, lq = lane >> 4;

    f32x4 acc[4][4];
#pragma unroll
    for (int m = 0; m < 4; ++m)
#pragma unroll
        for (int n = 0; n < 4; ++n){ f32x4 z = {0.f,0.f,0.f,0.f}; acc[m][n] = z; }

#pragma unroll
    for (int seg = 0; seg < 2; ++seg){
        const unsigned short* Ahi = seg ? Hhi : Xhi;
        const unsigned short* Alo = seg ? Hlo : Xlo;
        const int ldk = seg ? H_DIM : E_DIM;
        const int K   = seg ? H_DIM : E_DIM;
        const int kb  = seg ? E_DIM : 0;
        for (int k0 = 0; k0 < K; k0 += 64){
            stage64<128>(Ahi  + (size_t)brow*ldk + k0, ldk, ldsAhi);
            stage64<128>(Alo  + (size_t)brow*ldk + k0, ldk, ldsAlo);
            stage64<128>(WThi + (size_t)bcol*768 + kb + k0, 768, ldsBhi);
            stage64<128>(WTlo + (size_t)bcol*768 + kb + k0, 768, ldsBlo);
            __syncthreads();
#pragma unroll
            for (int kk = 0; kk < 2; ++kk){
                bf16x8 ahi[4], alo[4], bhi[4], blo[4];
#pragma unroll
                for (int m = 0; m < 4; ++m){
                    ahi[m] = ldsfrag(ldsAhi, wr*64 + m*16 + lr, kk*4 + lq);
                    alo[m] = ldsfrag(ldsAlo, wr*64 + m*16 + lr, kk*4 + lq);
                }
#pragma unroll
                for (int n = 0; n < 4; ++n){
                    bhi[n] = ldsfrag(ldsBhi, wc*64 + n*16 + lr, kk*4 + lq);
                    blo[n] = ldsfrag(ldsBlo, wc*64 + n*16 + lr, kk*4 + lq);
                }
#pragma unroll
                for (int m = 0; m < 4; ++m)
#pragma unroll
                    for (int n = 0; n < 4; ++n){
                        acc[m][n] = __builtin_amdgcn_mfma_f32_16x16x32_bf16(ahi[m], bhi[n], acc[m][n], 0,0,0);
                        acc[m][n] = __builtin_amdgcn_mfma_f32_16x16x32_bf16(alo[m], bhi[n], acc[m][n], 0,0,0);
                        acc[m][n] = __builtin_amdgcn_mfma_f32_16x16x32_bf16(ahi[m], blo[n], acc[m][n], 0,0,0);
                    }
            }
            __syncthreads();
        }
    }

    const int z = bcol >> 9;                 // gate index (tile never straddles)
    const int hbase = (bcol & 511) + wc*64;
    float* gz = gates + (size_t)z * BATCH * H_DIM;
#pragma unroll
    for (int m = 0; m < 4; ++m){
#pragma unroll
        for (int n = 0; n < 4; ++n){
            const int h = hbase + n*16 + lr;
            const float bs = bias[z*H_DIM + h];
#pragma unroll
            for (int r = 0; r < 4; ++r){
                const int b2 = brow + wr*64 + m*16 + lq*4 + r;
                float v = acc[m][n][r] + bs;
                v = (z < 3) ? sigmoidf_(v) : tanhf(v);
                gz[(size_t)b2 * H_DIM + h] = v;
            }
        }
    }
}

// ---------------------------------------------------------------------------
// Combine + full LSTM cell update, 3-term split precision on both GEMMs.
// acc1 = A1@B1T, acc2 = A2@B2T  (each [2048 x 512], K=512)
// mode 0 (click): shat=tanh((1-g)a1+g*a2); s=shat+i*gg+(1-g)*f*s; H=o*tanh(s)
// mode 1 (conv):  shat=tanh(a1+g*a2); s=shat+(1-g)*s+g*(f*s+i*gg);
//                 H=(1-g)*Hv32+g*(o*tanh(s)); Hv32=H
// Writes hi/lo bf16 H mirrors (ping-pong). 64x64 tile, 4 waves 2x2.
// ---------------------------------------------------------------------------
__global__ __launch_bounds__(256) void k_comb(
    const unsigned short* __restrict__ A1hi, const unsigned short* __restrict__ A1lo,
    const unsigned short* __restrict__ B1hi, const unsigned short* __restrict__ B1lo,
    const unsigned short* __restrict__ A2hi, const unsigned short* __restrict__ A2lo,
    const unsigned short* __restrict__ B2hi, const unsigned short* __restrict__ B2lo,
    const float* __restrict__ g, const float* __restrict__ gates,
    float* __restrict__ sstate, float* __restrict__ Hv32,
    unsigned short* __restrict__ Outhi, unsigned short* __restrict__ Outlo, int mode)
{
    __shared__ __align__(16) char lds[32768];
    char* ldsAhi = lds;
    char* ldsAlo = lds + 8192;
    char* ldsBhi = lds + 16384;
    char* ldsBlo = lds + 24576;
    const int tid = threadIdx.x;
    const int lane = tid & 63, wid = tid >> 6;
    const int wr = wid >> 1, wc = wid & 1;
    const int brow = blockIdx.y * 64, bcol = blockIdx.x * 64;
    const int lr = lane & 15, lq = lane >> 4;

    f32x4 acc1[2][2], acc2[2][2];
#pragma unroll
    for (int m = 0; m < 2; ++m)
#pragma unroll
        for (int n = 0; n < 2; ++n){ f32x4 z = {0.f,0.f,0.f,0.f}; acc1[m][n] = z; acc2[m][n] = z; }

#pragma unroll
    for (int seg = 0; seg < 2; ++seg){
        const unsigned short* Ahi = seg ? A2hi : A1hi;
        const unsigned short* Alo = seg ? A2lo : A1lo;
        const unsigned short* Bhi = seg ? B2hi : B1hi;
        const unsigned short* Blo = seg ? B2lo : B1lo;
        for (int k0 = 0; k0 < H_DIM; k0 += 64){
            stage64<64>(Ahi + (size_t)brow*H_DIM + k0, H_DIM, ldsAhi);
            stage64<64>(Alo + (size_t)brow*H_DIM + k0, H_DIM, ldsAlo);
            stage64<64>(Bhi + (size_t)bcol*H_DIM + k0, H_DIM, ldsBhi);
            stage64<64>(Blo + (size_t)bcol*H_DIM + k0, H_DIM, ldsBlo);
            __syncthreads();
#pragma unroll
            for (int kk = 0; kk < 2; ++kk){
                bf16x8 ahi[2], alo[2], bhi[2], blo[2];
#pragma unroll
                for (int m = 0; m < 2; ++m){
                    ahi[m] = ldsfrag(ldsAhi, wr*32 + m*16 + lr, kk*4 + lq);
                    alo[m] = ldsfrag(ldsAlo, wr*32 + m*16 + lr, kk*4 + lq);
                }
#pragma unroll
                for (int n = 0; n < 2; ++n){
                    bhi[n] = ldsfrag(ldsBhi, wc*32 + n*16 + lr, kk*4 + lq);
                    blo[n] = ldsfrag(ldsBlo, wc*32 + n*16 + lr, kk*4 + lq);
                }
#pragma unroll
                for (int m = 0; m < 2; ++m)
#pragma unroll
                    for (int n = 0; n < 2; ++n){
                        if (seg == 0){
                            acc1[m][n] = __builtin_amdgcn_mfma_f32_16x16x32_bf16(ahi[m], bhi[n], acc1[m][n], 0,0,0);
                            acc1[m][n] = __builtin_amdgcn_mfma_f32_16x16x32_bf16(alo[m], bhi[n], acc1[m][n], 0,0,0);
                            acc1[m][n] = __builtin_amdgcn_mfma_f32_16x16x32_bf16(ahi[m], blo[n], acc1[m][n], 0,0,0);
                        } else {
                            acc2[m][n] = __builtin_amdgcn_mfma_f32_16x16x32_bf16(ahi[m], bhi[n], acc2[m][n], 0,0,0);
                            acc2[m][n] = __builtin_amdgcn_mfma_f32_16x16x32_bf16(alo[m], bhi[n], acc2[m][n], 0,0,0);
                            acc2[m][n] = __builtin_amdgcn_mfma_f32_16x16x32_bf16(ahi[m], blo[n], acc2[m][n], 0,0,0);
                        }
                    }
            }
            __syncthreads();
        }
    }

    const size_t BH = (size_t)BATCH * H_DIM;
#pragma unroll
    for (int m = 0; m < 2; ++m){
#pragma unroll
        for (int n = 0; n < 2; ++n){
#pragma unroll
            for (int r = 0; r < 4; ++r){
                const int b2 = brow + wr*32 + m*16 + lq*4 + r;
                const int h  = bcol + wc*32 + n*16 + lr;
                const size_t idx = (size_t)b2 * H_DIM + h;
                const float gv = g[b2];
                const float a1 = acc1[m][n][r], a2 = acc2[m][n][r];
                const float f  = gates[idx];
                const float ii = gates[BH + idx];
                const float oo = gates[2*BH + idx];
                const float gg = gates[3*BH + idx];
                float hval;
                if (mode == 0){
                    const float shat = tanhf((1.0f - gv)*a1 + gv*a2);
                    const float s = shat + ii*gg + (1.0f - gv)*(f*sstate[idx]);
                    sstate[idx] = s;
                    hval = oo * tanhf(s);
                } else {
                    const float shat = tanhf(a1 + gv*a2);
                    const float svo = sstate[idx];
                    const float s = shat + (1.0f - gv)*svo + gv*(f*svo + ii*gg);
                    sstate[idx] = s;
                    hval = (1.0f - gv)*Hv32[idx] + gv*(oo * tanhf(s));
                    Hv32[idx] = hval;
                }
                unsigned short hh, hl;
                splitbf(hval, hh, hl);
                Outhi[idx] = hh;
                Outlo[idx] = hl;
            }
        }
    }
}

// ---------------------------------------------------------------------------
// Fused predict (single bf16 — non-recurrent error path):
// p0=leaky(H@W0+b0), p1=leaky(p0@W1+b1), val=sigmoid(dot(p1,Wf)+bf) (*gmul).
// BM=32 rows/block, 64 blocks, 4 waves.
// ---------------------------------------------------------------------------
__global__ __launch_bounds__(256) void k_predict(
    const unsigned short* __restrict__ Hbf,   // hi mirror [2048][512]
    const unsigned short* __restrict__ W0T,   // [256][512]
    const float* __restrict__ b0,             // [256]
    const unsigned short* __restrict__ W1T,   // [128][256]
    const float* __restrict__ b1,             // [128]
    const float* __restrict__ Wf,             // [128]
    const float* __restrict__ bf_,            // [1]
    float* gstate, const float* __restrict__ gmul, float* pred)
{
    __shared__ __align__(16) char lds[53760];
    char*  ldsA = lds;              // [32][128B]
    char*  ldsB = lds + 4096;       // up to [256][128B]
    char*  ldsP = lds + 36864;      // [32][512B] p0 bf16 (swizzled)
    float* sums = (float*)(lds + 53248);  // [4][32]
    const int tid = threadIdx.x, lane = tid & 63, w = tid >> 6;
    const int lr = lane & 15, lq = lane >> 4;
    const int brow = blockIdx.x * 32;

    // ---- p0 GEMM: [32 x 256], K=512 ----
    f32x4 acc0[2][4];
#pragma unroll
    for (int m = 0; m < 2; ++m)
#pragma unroll
        for (int n = 0; n < 4; ++n){ f32x4 z = {0.f,0.f,0.f,0.f}; acc0[m][n] = z; }

    for (int k0 = 0; k0 < H_DIM; k0 += 64){
        stage64<32>(Hbf + (size_t)brow*H_DIM + k0, H_DIM, ldsA);
        stage64<256>(W0T + k0, H_DIM, ldsB);
        __syncthreads();
#pragma unroll
        for (int kk = 0; kk < 2; ++kk){
            bf16x8 a[2], b[4];
#pragma unroll
            for (int m = 0; m < 2; ++m) a[m] = ldsfrag(ldsA, m*16 + lr, kk*4 + lq);
#pragma unroll
            for (int n = 0; n < 4; ++n) b[n] = ldsfrag(ldsB, w*64 + n*16 + lr, kk*4 + lq);
#pragma unroll
            for (int m = 0; m < 2; ++m)
#pragma unroll
                for (int n = 0; n < 4; ++n)
                    acc0[m][n] = __builtin_amdgcn_mfma_f32_16x16x32_bf16(a[m], b[n], acc0[m][n], 0,0,0);
        }
        __syncthreads();
    }
    // p0 epilogue -> swizzled bf16 in ldsP
#pragma unroll
    for (int m = 0; m < 2; ++m){
#pragma unroll
        for (int n = 0; n < 4; ++n){
            const int col = w*64 + n*16 + lr;
            const float bs = b0[col];
#pragma unroll
            for (int r = 0; r < 4; ++r){
                const int row = m*16 + lq*4 + r;
                float x = acc0[m][n][r] + bs;
                x = (x > 0.0f) ? x : ALPHA*x;
                *(unsigned short*)(ldsP + row*512 + ((((col>>3)) ^ (row&7)) << 4) + (col&7)*2) = f2bf(x);
            }
        }
    }
    __syncthreads();

    // ---- p1 GEMM: [32 x 128], K=256, A from ldsP ----
    f32x4 accp[2][2];
#pragma unroll
    for (int m = 0; m < 2; ++m)
#pragma unroll
        for (int n = 0; n < 2; ++n){ f32x4 z = {0.f,0.f,0.f,0.f}; accp[m][n] = z; }

    for (int k0 = 0; k0 < P0_DIM; k0 += 64){
        stage64<128>(W1T + k0, P0_DIM, ldsB);
        __syncthreads();
#pragma unroll
        for (int kk = 0; kk < 2; ++kk){
            bf16x8 a[2], b[2];
#pragma unroll
            for (int m = 0; m < 2; ++m){
                const int row = m*16 + lr;
                const int slot = (k0 >> 3) + kk*4 + lq;
                a[m] = *(const bf16x8*)(ldsP + row*512 + ((slot ^ (row & 7)) << 4));
            }
#pragma unroll
            for (int n = 0; n < 2; ++n) b[n] = ldsfrag(ldsB, w*32 + n*16 + lr, kk*4 + lq);
#pragma unroll
            for (int m = 0; m < 2; ++m)
#pragma unroll
                for (int n = 0; n < 2; ++n)
                    accp[m][n] = __builtin_amdgcn_mfma_f32_16x16x32_bf16(a[m], b[n], accp[m][n], 0,0,0);
        }
        __syncthreads();
    }

    // ---- head ----
    float part[8];
#pragma unroll
    for (int j = 0; j < 8; ++j) part[j] = 0.0f;
#pragma unroll
    for (int m = 0; m < 2; ++m){
#pragma unroll
        for (int n = 0; n < 2; ++n){
            const int col = w*32 + n*16 + lr;
            const float bs = b1[col], wf = Wf[col];
#pragma unroll
            for (int r = 0; r < 4; ++r){
                float x = accp[m][n][r] + bs;
                x = (x > 0.0f) ? x : ALPHA*x;
                part[m*4 + r] += x * wf;
            }
        }
    }
#pragma unroll
    for (int mask = 1; mask < 16; mask <<= 1)
#pragma unroll
        for (int j = 0; j < 8; ++j) part[j] += __shfl_xor(part[j], mask);
    if (lr == 0){
#pragma unroll
        for (int j = 0; j < 8; ++j){
            const int row = (j >> 2)*16 + lq*4 + (j & 3);
            sums[w*32 + row] = part[j];
        }
    }
    __syncthreads();
    if (tid < 32){
        float tot = sums[tid] + sums[32 + tid] + sums[64 + tid] + sums[96 + tid] + bf_[0];
        float val = sigmoidf_(tot);
        const int rowg = brow + tid;
        if (gmul)   val *= gmul[rowg];
        if (gstate) gstate[rowg] = val;
        if (pred)   pred[rowg]   = val;
    }
}

// ---------------------------------------------------------------------------
// Prep / utility kernels
// ---------------------------------------------------------------------------
__global__ __launch_bounds__(256) void k_xcvt(const float* __restrict__ x,
                                              unsigned short* __restrict__ ohi,
                                              unsigned short* __restrict__ olo){
    const int t = blockIdx.x*256 + threadIdx.x;       // 4 elems each
    float4 v = ((const float4*)x)[t];
    ushort4 h, l;
    splitbf(v.x, h.x, l.x); splitbf(v.y, h.y, l.y);
    splitbf(v.z, h.z, l.z); splitbf(v.w, h.w, l.w);
    ((ushort4*)ohi)[t] = h;
    ((ushort4*)olo)[t] = l;
}

// WcatT [2048][768]: n=z*512+h; k<256 -> Wx[z][k][h], else Wh[z][k-256][h]
__global__ __launch_bounds__(256) void k_wcat(const float* __restrict__ Wx,
                                              const float* __restrict__ Wh,
                                              unsigned short* __restrict__ ohi,
                                              unsigned short* __restrict__ olo){
    const int n = blockIdx.y;
    const int k = blockIdx.x*256 + threadIdx.x;
    const int z = n >> 9, h = n & 511;
    float v = (k < 256) ? Wx[((size_t)z*E_DIM + k)*H_DIM + h]
                        : Wh[((size_t)z*H_DIM + (k - 256))*H_DIM + h];
    unsigned short hh, hl;
    splitbf(v, hh, hl);
    ohi[(size_t)n*768 + k] = hh;
    olo[(size_t)n*768 + k] = hl;
}

// out [N][K] bf16 hi/lo = transpose(in [K][N] f32)
__global__ __launch_bounds__(256) void k_trans(const float* __restrict__ in,
                                               unsigned short* __restrict__ ohi,
                                               unsigned short* __restrict__ olo,
                                               int K, int N){
    const int k = blockIdx.x*256 + threadIdx.x;
    const int n = blockIdx.y;
    if (k < K){
        unsigned short hh, hl;
        splitbf(in[(size_t)k*N + n], hh, hl);
        ohi[(size_t)n*K + k] = hh;
        olo[(size_t)n*K + k] = hl;
    }
}

__global__ __launch_bounds__(256) void k_init(float* __restrict__ sc, float* __restrict__ sv,
                                              float* __restrict__ hv32,
                                              unsigned short* __restrict__ hc0hi,
                                              unsigned short* __restrict__ hc0lo,
                                              unsigned short* __restrict__ hv0hi,
                                              unsigned short* __restrict__ hv0lo){
    const int i = blockIdx.x*256 + threadIdx.x;
    sc[i] = 0.0f; sv[i] = 0.0f; hv32[i] = 0.0f;
    hc0hi[i] = 0; hc0lo[i] = 0; hv0hi[i] = 0; hv0lo[i] = 0;
}

// ---------------------------------------------------------------------------
extern "C" void kernel_launch(void* const* d_in, const int* in_sizes, int n_in,
                              void* d_out, int out_size, void* d_ws, size_t ws_size,
                              hipStream_t stream)
{
    (void)in_sizes; (void)n_in; (void)out_size; (void)ws_size;

    const float* inputs = (const float*)d_in[0];
    const float* Wx_c   = (const float*)d_in[1];
    const float* bx_c   = (const float*)d_in[2];
    const float* Wh_c   = (const float*)d_in[3];
    const float* Wx_v   = (const float*)d_in[4];
    const float* bx_v   = (const float*)d_in[5];
    const float* Wh_v   = (const float*)d_in[6];
    const float* Ws     = (const float*)d_in[7];
    const float* Wpc0   = (const float*)d_in[8];
    const float* bpc0   = (const float*)d_in[9];
    const float* Wpc1   = (const float*)d_in[10];
    const float* bpc1   = (const float*)d_in[11];
    const float* Wfcc   = (const float*)d_in[12];
    const float* bfcc   = (const float*)d_in[13];
    const float* Wpv0   = (const float*)d_in[14];
    const float* bpv0   = (const float*)d_in[15];
    const float* Wpv1   = (const float*)d_in[16];
    const float* bpv1   = (const float*)d_in[17];
    const float* Wfcv   = (const float*)d_in[18];
    const float* bfcv   = (const float*)d_in[19];
    float* out = (float*)d_out;

    char* ws = (char*)d_ws;
    size_t off = 0;
    auto allocB = [&](size_t bytes) -> char* {
        char* p = ws + off;
        off = (off + bytes + 255) & ~(size_t)255;
        return p;
    };
    const size_t BH = (size_t)BATCH * H_DIM;

    unsigned short* Xhi     = (unsigned short*)allocB((size_t)BATCH*E_DIM*2);
    unsigned short* Xlo     = (unsigned short*)allocB((size_t)BATCH*E_DIM*2);
    unsigned short* WcTc_hi = (unsigned short*)allocB((size_t)2048*768*2);
    unsigned short* WcTc_lo = (unsigned short*)allocB((size_t)2048*768*2);
    unsigned short* WcTv_hi = (unsigned short*)allocB((size_t)2048*768*2);
    unsigned short* WcTv_lo = (unsigned short*)allocB((size_t)2048*768*2);
    unsigned short* WsT_hi  = (unsigned short*)allocB((size_t)4*H_DIM*H_DIM*2);
    unsigned short* WsT_lo  = (unsigned short*)allocB((size_t)4*H_DIM*H_DIM*2);
    unsigned short* Wp0Tc_h = (unsigned short*)allocB((size_t)P0_DIM*H_DIM*2);
    unsigned short* Wp0Tc_l = (unsigned short*)allocB((size_t)P0_DIM*H_DIM*2);
    unsigned short* Wp0Tv_h = (unsigned short*)allocB((size_t)P0_DIM*H_DIM*2);
    unsigned short* Wp0Tv_l = (unsigned short*)allocB((size_t)P0_DIM*H_DIM*2);
    unsigned short* Wp1Tc_h = (unsigned short*)allocB((size_t)P1_DIM*P0_DIM*2);
    unsigned short* Wp1Tc_l = (unsigned short*)allocB((size_t)P1_DIM*P0_DIM*2);
    unsigned short* Wp1Tv_h = (unsigned short*)allocB((size_t)P1_DIM*P0_DIM*2);
    unsigned short* Wp1Tv_l = (unsigned short*)allocB((size_t)P1_DIM*P0_DIM*2);
    unsigned short *Hchi[2], *Hclo[2], *Hvhi[2], *Hvlo[2];
    for (int i = 0; i < 2; ++i){
        Hchi[i] = (unsigned short*)allocB(BH*2);
        Hclo[i] = (unsigned short*)allocB(BH*2);
        Hvhi[i] = (unsigned short*)allocB(BH*2);
        Hvlo[i] = (unsigned short*)allocB(BH*2);
    }
    float* sc    = (float*)allocB(BH*4);
    float* sv    = (float*)allocB(BH*4);
    float* hv32  = (float*)allocB(BH*4);
    float* gates = (float*)allocB(4*BH*4);
    float* g     = (float*)allocB(BATCH*4);

    const dim3 thr(256);
    const size_t HH = (size_t)H_DIM * H_DIM;

    // ---- one-time (per launch) weight conversion ----
    k_wcat<<<dim3(3, 2048), thr, 0, stream>>>(Wx_c, Wh_c, WcTc_hi, WcTc_lo);
    k_wcat<<<dim3(3, 2048), thr, 0, stream>>>(Wx_v, Wh_v, WcTv_hi, WcTv_lo);
    for (int i = 0; i < 4; ++i)
        k_trans<<<dim3(2, 512), thr, 0, stream>>>(Ws + i*HH, WsT_hi + i*HH, WsT_lo + i*HH,
                                                  H_DIM, H_DIM);
    k_trans<<<dim3(2, 256), thr, 0, stream>>>(Wpc0, Wp0Tc_h, Wp0Tc_l, H_DIM, P0_DIM);
    k_trans<<<dim3(2, 256), thr, 0, stream>>>(Wpv0, Wp0Tv_h, Wp0Tv_l, H_DIM, P0_DIM);
    k_trans<<<dim3(1, 128), thr, 0, stream>>>(Wpc1, Wp1Tc_h, Wp1Tc_l, P0_DIM, P1_DIM);
    k_trans<<<dim3(1, 128), thr, 0, stream>>>(Wpv1, Wp1Tv_h, Wp1Tv_l, P0_DIM, P1_DIM);

    // ---- init: zero states, g0 = predict_c(zeros) ----
    k_init<<<4096, thr, 0, stream>>>(sc, sv, hv32, Hchi[0], Hclo[0], Hvhi[0], Hvlo[0]);
    k_predict<<<64, thr, 0, stream>>>(Hchi[0], Wp0Tc_h, bpc0, Wp1Tc_h, bpc1, Wfcc, bfcc,
                                      g, nullptr, nullptr);

    for (int t = 0; t < T_STEPS; ++t){
        const int o = t & 1, nn = o ^ 1;
        k_xcvt<<<512, thr, 0, stream>>>(inputs + (size_t)t*BATCH*E_DIM, Xhi, Xlo);

        // click stream
        k_gates<<<dim3(16,16), thr, 0, stream>>>(Xhi, Xlo, Hchi[o], Hclo[o],
                                                 WcTc_hi, WcTc_lo, bx_c, gates);
        k_comb<<<dim3(8,32), thr, 0, stream>>>(Hchi[o], Hclo[o], WsT_hi + 0*HH, WsT_lo + 0*HH,
                                               Hvhi[o], Hvlo[o], WsT_hi + 1*HH, WsT_lo + 1*HH,
                                               g, gates, sc, nullptr,
                                               Hchi[nn], Hclo[nn], 0);
        k_predict<<<64, thr, 0, stream>>>(Hchi[nn], Wp0Tc_h, bpc0, Wp1Tc_h, bpc1, Wfcc, bfcc,
                                          g, nullptr, out + (size_t)t*BATCH);

        // conversion stream
        k_gates<<<dim3(16,16), thr, 0, stream>>>(Xhi, Xlo, Hchi[nn], Hclo[nn],
                                                 WcTv_hi, WcTv_lo, bx_v, gates);
        k_comb<<<dim3(8,32), thr, 0, stream>>>(Hvhi[o], Hvlo[o], WsT_hi + 2*HH, WsT_lo + 2*HH,
                                               Hchi[nn], Hclo[nn], WsT_hi + 3*HH, WsT_lo + 3*HH,
                                               g, gates, sv, hv32,
                                               Hvhi[nn], Hvlo[nn], 1);
        k_predict<<<64, thr, 0, stream>>>(Hvhi[nn], Wp0Tv_h, bpv0, Wp1Tv_h, bpv1, Wfcv, bfcv,
                                          nullptr, g, out + (size_t)(T_STEPS + t)*BATCH);
    }
}

// Round 4
// 26875.552 us; speedup vs baseline: 3.1379x; 1.1915x over previous
//
#include <hip/hip_runtime.h>
#include <cstdint>
#include <cstddef>

constexpr int T_STEPS = 200;
constexpr int BATCH   = 2048;
constexpr int E_DIM   = 256;
constexpr int H_DIM   = 512;
constexpr int P0_DIM  = 256;
constexpr int P1_DIM  = 128;
constexpr float ALPHA = 0.3f;

typedef __attribute__((ext_vector_type(8))) short bf16x8;
typedef __attribute__((ext_vector_type(4))) float f32x4;

__device__ __forceinline__ float sigmoidf_(float x){ return 1.0f/(1.0f+expf(-x)); }

__device__ __forceinline__ unsigned short f2bf(float f){
    union { float f; unsigned u; } v; v.f = f;
    unsigned r = (v.u + 0x7FFFu + ((v.u >> 16) & 1u)) >> 16;   // RNE
    return (unsigned short)r;
}
__device__ __forceinline__ float bf2f(unsigned short h){
    union { unsigned u; float f; } v; v.u = ((unsigned)h) << 16; return v.f;
}
__device__ __forceinline__ void splitbf(float x, unsigned short& hi, unsigned short& lo){
    hi = f2bf(x);
    lo = f2bf(x - bf2f(hi));
}

#define GLOAD16(gp, lp) __builtin_amdgcn_global_load_lds( \
    (const __attribute__((address_space(1))) unsigned int*)(gp), \
    (__attribute__((address_space(3))) unsigned int*)(lp), 16, 0, 0)

// Stage a [ROWS][64] bf16 tile into linear LDS, slot-swizzled at the SOURCE
// (m173 pattern): LDS[r][s] holds global k-slot (s ^ (r&7)) of row r.
template<int ROWS>
__device__ __forceinline__ void stage64(const unsigned short* __restrict__ src, int ldk,
                                        char* ldsbase){
    constexpr int TOT = ROWS * 8;          // 16B slots
    const int tid = threadIdx.x;
#pragma unroll
    for (int i = 0; i < TOT/256; ++i){
        const int gsl = i*256 + tid;
        const int r = gsl >> 3, s = gsl & 7;
        const int ksrc = ((s ^ (r & 7)) << 3);
        GLOAD16(src + (size_t)r*ldk + ksrc, ldsbase + gsl*16);
    }
}

// Swizzled b128 fragment read: row-stride 128B (BK=64), kslot in [0,8).
__device__ __forceinline__ bf16x8 ldsfrag(const char* ldsbase, int row, int kslot){
    return *(const bf16x8*)(ldsbase + row*128 + ((kslot ^ (row & 7)) << 4));
}

// ---------------------------------------------------------------------------
// 128x128-tile 3-term split K-loop: acc += Ahi@B'hi + Alo@B'hi + Ahi@B'lo
// A/B pointers pre-offset to (tile_row0, 0) / (tile_col0, 0).
// ---------------------------------------------------------------------------
__device__ __forceinline__ void mm_loop128(
    const unsigned short* __restrict__ Ahi, const unsigned short* __restrict__ Alo, int lda,
    const unsigned short* __restrict__ Bhi, const unsigned short* __restrict__ Blo, int ldb,
    int K, f32x4 (&acc)[4][4], char* lds, int wr, int wc, int lr, int lq)
{
    char* ldsAhi = lds;
    char* ldsAlo = lds + 16384;
    char* ldsBhi = lds + 32768;
    char* ldsBlo = lds + 49152;
    for (int k0 = 0; k0 < K; k0 += 64){
        stage64<128>(Ahi + k0, lda, ldsAhi);
        stage64<128>(Alo + k0, lda, ldsAlo);
        stage64<128>(Bhi + k0, ldb, ldsBhi);
        stage64<128>(Blo + k0, ldb, ldsBlo);
        __syncthreads();
#pragma unroll
        for (int kk = 0; kk < 2; ++kk){
            bf16x8 ahi[4], alo[4], bhi[4], blo[4];
#pragma unroll
            for (int m = 0; m < 4; ++m){
                ahi[m] = ldsfrag(ldsAhi, wr*64 + m*16 + lr, kk*4 + lq);
                alo[m] = ldsfrag(ldsAlo, wr*64 + m*16 + lr, kk*4 + lq);
            }
#pragma unroll
            for (int n = 0; n < 4; ++n){
                bhi[n] = ldsfrag(ldsBhi, wc*64 + n*16 + lr, kk*4 + lq);
                blo[n] = ldsfrag(ldsBlo, wc*64 + n*16 + lr, kk*4 + lq);
            }
#pragma unroll
            for (int m = 0; m < 4; ++m)
#pragma unroll
                for (int n = 0; n < 4; ++n){
                    acc[m][n] = __builtin_amdgcn_mfma_f32_16x16x32_bf16(ahi[m], bhi[n], acc[m][n], 0,0,0);
                    acc[m][n] = __builtin_amdgcn_mfma_f32_16x16x32_bf16(alo[m], bhi[n], acc[m][n], 0,0,0);
                    acc[m][n] = __builtin_amdgcn_mfma_f32_16x16x32_bf16(ahi[m], blo[n], acc[m][n], 0,0,0);
                }
        }
        __syncthreads();
    }
}

// ---------------------------------------------------------------------------
// One launch per stream: all step-t GEMMs (independent: read only prev state).
//  blocks [0,256):   gates = act(x@Wx + H@Wh + bias)      (M=2048,N=2048,K=768)
//  blocks [256,320): a1 = C1A @ C1B^T                      (M=2048,N=512,K=512)
//  blocks [320,384): a2 = C2A @ C2B^T
// ---------------------------------------------------------------------------
__global__ __launch_bounds__(256, 2) void k_mm(
    const unsigned short* __restrict__ Xhi,  const unsigned short* __restrict__ Xlo,
    const unsigned short* __restrict__ Hahi, const unsigned short* __restrict__ Halo,
    const unsigned short* __restrict__ WThi, const unsigned short* __restrict__ WTlo,
    const float* __restrict__ bias, float* __restrict__ gates,
    const unsigned short* __restrict__ C1Ahi, const unsigned short* __restrict__ C1Alo,
    const unsigned short* __restrict__ C1Bhi, const unsigned short* __restrict__ C1Blo,
    float* __restrict__ a1,
    const unsigned short* __restrict__ C2Ahi, const unsigned short* __restrict__ C2Alo,
    const unsigned short* __restrict__ C2Bhi, const unsigned short* __restrict__ C2Blo,
    float* __restrict__ a2)
{
    __shared__ __align__(16) char lds[65536];
    const int tid = threadIdx.x;
    const int lane = tid & 63, wid = tid >> 6;
    const int wr = wid >> 1, wc = wid & 1;
    const int lr = lane & 15, lq = lane >> 4;
    const int id = blockIdx.x;

    f32x4 acc[4][4];
#pragma unroll
    for (int m = 0; m < 4; ++m)
#pragma unroll
        for (int n = 0; n < 4; ++n){ f32x4 z = {0.f,0.f,0.f,0.f}; acc[m][n] = z; }

    if (id < 256){
        const int brow = (id >> 4) * 128, bcol = (id & 15) * 128;
        mm_loop128(Xhi  + (size_t)brow*E_DIM, Xlo  + (size_t)brow*E_DIM, E_DIM,
                   WThi + (size_t)bcol*768,   WTlo + (size_t)bcol*768,   768,
                   E_DIM, acc, lds, wr, wc, lr, lq);
        mm_loop128(Hahi + (size_t)brow*H_DIM, Halo + (size_t)brow*H_DIM, H_DIM,
                   WThi + (size_t)bcol*768 + E_DIM, WTlo + (size_t)bcol*768 + E_DIM, 768,
                   H_DIM, acc, lds, wr, wc, lr, lq);

        const int z = bcol >> 9;
        const int hbase = (bcol & 511) + wc*64;
        float* gz = gates + (size_t)z * BATCH * H_DIM;
#pragma unroll
        for (int m = 0; m < 4; ++m){
#pragma unroll
            for (int n = 0; n < 4; ++n){
                const int h = hbase + n*16 + lr;
                const float bs = bias[z*H_DIM + h];
#pragma unroll
                for (int r = 0; r < 4; ++r){
                    const int b2 = brow + wr*64 + m*16 + lq*4 + r;
                    float v = acc[m][n][r] + bs;
                    v = (z < 3) ? sigmoidf_(v) : tanhf(v);
                    gz[(size_t)b2 * H_DIM + h] = v;
                }
            }
        }
    } else {
        const int id2 = id - 256;
        const int job = id2 >> 6, jid = id2 & 63;
        const int brow = (jid >> 2) * 128, bcol = (jid & 3) * 128;
        const unsigned short* Ahi = job ? C2Ahi : C1Ahi;
        const unsigned short* Alo = job ? C2Alo : C1Alo;
        const unsigned short* Bhi = job ? C2Bhi : C1Bhi;
        const unsigned short* Blo = job ? C2Blo : C1Blo;
        float* outp = job ? a2 : a1;
        mm_loop128(Ahi + (size_t)brow*H_DIM, Alo + (size_t)brow*H_DIM, H_DIM,
                   Bhi + (size_t)bcol*H_DIM, Blo + (size_t)bcol*H_DIM, H_DIM,
                   H_DIM, acc, lds, wr, wc, lr, lq);
#pragma unroll
        for (int m = 0; m < 4; ++m){
#pragma unroll
            for (int n = 0; n < 4; ++n){
                const int h = bcol + wc*64 + n*16 + lr;
#pragma unroll
                for (int r = 0; r < 4; ++r){
                    const int b2 = brow + wr*64 + m*16 + lq*4 + r;
                    outp[(size_t)b2 * H_DIM + h] = acc[m][n][r];
                }
            }
        }
    }
}

// ---------------------------------------------------------------------------
// Fused cell update + predict. 128 blocks x 16 rows.
// mode 0 (click): cell_c, writes Hc hi/lo + g + pred
// mode 1 (conv):  cell_v, writes Hv hi/lo + pred = val*g  (g untouched)
// mode 2 (init):  H = 0, predict only, writes g
// ---------------------------------------------------------------------------
__global__ __launch_bounds__(256) void k_cellpred(
    const int mode,
    const float* __restrict__ gates, const float* __restrict__ a1, const float* __restrict__ a2,
    float* __restrict__ g, float* __restrict__ sstate, float* __restrict__ Hv32,
    unsigned short* __restrict__ Outhi, unsigned short* __restrict__ Outlo,
    const unsigned short* __restrict__ W0T, const float* __restrict__ b0,
    const unsigned short* __restrict__ W1T, const float* __restrict__ b1,
    const float* __restrict__ Wf, const float* __restrict__ bf_,
    float* __restrict__ pred)
{
    __shared__ __align__(16) char lds[57600];
    char*  Hlds = lds;                    // [16][1024B] bf16 H, slot-swizzled
    char*  Bbuf = lds + 16384;            // up to 32KB B-tiles
    char*  ldsP = lds + 49152;            // [16][512B]  p0 bf16, slot-swizzled
    float* sums = (float*)(lds + 57344);  // [4][16]
    const int tid = threadIdx.x, lane = tid & 63, w = tid >> 6;
    const int lr = lane & 15, lq = lane >> 4;
    const int brow = blockIdx.x * 16;
    const size_t BH = (size_t)BATCH * H_DIM;

    if (mode == 2){
        // H = 0 in LDS
        int4 z4 = {0,0,0,0};
#pragma unroll
        for (int j = 0; j < 4; ++j) ((int4*)Hlds)[tid*4 + j] = z4;
    } else {
        // ---- cell phase: this block's 16 rows x 512 cols ----
        const int row16 = tid >> 4, cg = tid & 15;
        const int row = brow + row16;
        const float gv = g[row];
#pragma unroll
        for (int j = 0; j < 4; ++j){
            const int c = cg*32 + j*8;
            const size_t idx = (size_t)row*H_DIM + c;
            union { float4 v[2]; float s[8]; } f_, i_, o_, q_, u1, u2, sv;
            f_.v[0] = *(const float4*)&gates[idx];        f_.v[1] = *(const float4*)&gates[idx+4];
            i_.v[0] = *(const float4*)&gates[BH+idx];     i_.v[1] = *(const float4*)&gates[BH+idx+4];
            o_.v[0] = *(const float4*)&gates[2*BH+idx];   o_.v[1] = *(const float4*)&gates[2*BH+idx+4];
            q_.v[0] = *(const float4*)&gates[3*BH+idx];   q_.v[1] = *(const float4*)&gates[3*BH+idx+4];
            u1.v[0] = *(const float4*)&a1[idx];           u1.v[1] = *(const float4*)&a1[idx+4];
            u2.v[0] = *(const float4*)&a2[idx];           u2.v[1] = *(const float4*)&a2[idx+4];
            sv.v[0] = *(const float4*)&sstate[idx];       sv.v[1] = *(const float4*)&sstate[idx+4];
            union { unsigned short u[8]; bf16x8 v; } hh, hl;
            union { float4 v[2]; float s[8]; } sn, hv;
#pragma unroll
            for (int e = 0; e < 8; ++e){
                float hval, s;
                if (mode == 0){
                    const float shat = tanhf((1.0f - gv)*u1.s[e] + gv*u2.s[e]);
                    s = shat + i_.s[e]*q_.s[e] + (1.0f - gv)*(f_.s[e]*sv.s[e]);
                    hval = o_.s[e] * tanhf(s);
                } else {
                    const float shat = tanhf(u1.s[e] + gv*u2.s[e]);
                    const float svo = sv.s[e];
                    s = shat + (1.0f - gv)*svo + gv*(f_.s[e]*svo + i_.s[e]*q_.s[e]);
                    hval = (1.0f - gv)*Hv32[idx + e] + gv*(o_.s[e]*tanhf(s));
                    Hv32[idx + e] = hval;
                }
                sn.s[e] = s;
                hv.s[e] = hval;
                splitbf(hval, hh.u[e], hl.u[e]);
            }
            *(float4*)&sstate[idx]     = sn.v[0];
            *(float4*)&sstate[idx + 4] = sn.v[1];
            *(bf16x8*)&Outhi[idx] = hh.v;
            *(bf16x8*)&Outlo[idx] = hl.v;
            // LDS stash (p0 A-tile), slot-swizzled: slot = c/8 in [0,64)
            *(bf16x8*)(Hlds + row16*1024 + ((((c >> 3)) ^ (row16 & 7)) << 4)) = hh.v;
        }
    }
    __syncthreads();

    // ---- p0: [16 x 256] = Hlds @ W0T^T, K=512 ----
    f32x4 acc0[4];
#pragma unroll
    for (int n = 0; n < 4; ++n){ f32x4 z = {0.f,0.f,0.f,0.f}; acc0[n] = z; }
    for (int k0 = 0; k0 < H_DIM; k0 += 64){
        stage64<256>(W0T + k0, H_DIM, Bbuf);
        __syncthreads();
#pragma unroll
        for (int kk = 0; kk < 2; ++kk){
            const int gslot = (k0 >> 3) + kk*4 + lq;
            bf16x8 a = *(const bf16x8*)(Hlds + lr*1024 + ((gslot ^ (lr & 7)) << 4));
#pragma unroll
            for (int n = 0; n < 4; ++n){
                bf16x8 b = ldsfrag(Bbuf, w*64 + n*16 + lr, kk*4 + lq);
                acc0[n] = __builtin_amdgcn_mfma_f32_16x16x32_bf16(a, b, acc0[n], 0,0,0);
            }
        }
        __syncthreads();
    }
    // p0 epilogue -> ldsP
#pragma unroll
    for (int n = 0; n < 4; ++n){
        const int col = w*64 + n*16 + lr;
        const float bs = b0[col];
#pragma unroll
        for (int r = 0; r < 4; ++r){
            const int row = lq*4 + r;
            float x = acc0[n][r] + bs;
            x = (x > 0.0f) ? x : ALPHA*x;
            *(unsigned short*)(ldsP + row*512 + ((((col >> 3)) ^ (row & 7)) << 4) + (col & 7)*2) = f2bf(x);
        }
    }
    __syncthreads();

    // ---- p1: [16 x 128] = ldsP @ W1T^T, K=256 ----
    f32x4 accp[2];
#pragma unroll
    for (int n = 0; n < 2; ++n){ f32x4 z = {0.f,0.f,0.f,0.f}; accp[n] = z; }
    for (int k0 = 0; k0 < P0_DIM; k0 += 64){
        stage64<128>(W1T + k0, P0_DIM, Bbuf);
        __syncthreads();
#pragma unroll
        for (int kk = 0; kk < 2; ++kk){
            const int gslot = (k0 >> 3) + kk*4 + lq;
            bf16x8 a = *(const bf16x8*)(ldsP + lr*512 + ((gslot ^ (lr & 7)) << 4));
#pragma unroll
            for (int n = 0; n < 2; ++n){
                bf16x8 b = ldsfrag(Bbuf, w*32 + n*16 + lr, kk*4 + lq);
                accp[n] = __builtin_amdgcn_mfma_f32_16x16x32_bf16(a, b, accp[n], 0,0,0);
            }
        }
        __syncthreads();
    }

    // ---- head ----
    float part[4] = {0.f, 0.f, 0.f, 0.f};
#pragma unroll
    for (int n = 0; n < 2; ++n){
        const int col = w*32 + n*16 + lr;
        const float bs = b1[col], wf = Wf[col];
#pragma unroll
        for (int r = 0; r < 4; ++r){
            float x = accp[n][r] + bs;
            x = (x > 0.0f) ? x : ALPHA*x;
            part[r] += x * wf;
        }
    }
#pragma unroll
    for (int mask = 1; mask < 16; mask <<= 1)
#pragma unroll
        for (int r = 0; r < 4; ++r) part[r] += __shfl_xor(part[r], mask);
    if (lr == 0){
#pragma unroll
        for (int r = 0; r < 4; ++r) sums[w*16 + lq*4 + r] = part[r];
    }
    __syncthreads();
    if (tid < 16){
        const float tot = sums[tid] + sums[16 + tid] + sums[32 + tid] + sums[48 + tid] + bf_[0];
        float val = sigmoidf_(tot);
        const int rowg = brow + tid;
        if (mode == 0){ g[rowg] = val; pred[rowg] = val; }
        else if (mode == 1){ pred[rowg] = val * g[rowg]; }
        else { g[rowg] = val; }
    }
}

// ---------------------------------------------------------------------------
// Prep / utility kernels
// ---------------------------------------------------------------------------
// Convert 4 steps of x to hi/lo bf16 (grid 2048 x 256, 4 floats/thread).
__global__ __launch_bounds__(256) void k_xcvt4(const float* __restrict__ x,
                                               unsigned short* __restrict__ ohi,
                                               unsigned short* __restrict__ olo){
    const int t = blockIdx.x*256 + threadIdx.x;
    float4 v = ((const float4*)x)[t];
    ushort4 h, l;
    splitbf(v.x, h.x, l.x); splitbf(v.y, h.y, l.y);
    splitbf(v.z, h.z, l.z); splitbf(v.w, h.w, l.w);
    ((ushort4*)ohi)[t] = h;
    ((ushort4*)olo)[t] = l;
}

// WcatT [2048][768]: n=z*512+h; k<256 -> Wx[z][k][h], else Wh[z][k-256][h]
__global__ __launch_bounds__(256) void k_wcat(const float* __restrict__ Wx,
                                              const float* __restrict__ Wh,
                                              unsigned short* __restrict__ ohi,
                                              unsigned short* __restrict__ olo){
    const int n = blockIdx.y;
    const int k = blockIdx.x*256 + threadIdx.x;
    const int z = n >> 9, h = n & 511;
    float v = (k < 256) ? Wx[((size_t)z*E_DIM + k)*H_DIM + h]
                        : Wh[((size_t)z*H_DIM + (k - 256))*H_DIM + h];
    unsigned short hh, hl;
    splitbf(v, hh, hl);
    ohi[(size_t)n*768 + k] = hh;
    olo[(size_t)n*768 + k] = hl;
}

// out [N][K] bf16 hi/lo = transpose(in [K][N] f32)
__global__ __launch_bounds__(256) void k_trans(const float* __restrict__ in,
                                               unsigned short* __restrict__ ohi,
                                               unsigned short* __restrict__ olo,
                                               int K, int N){
    const int k = blockIdx.x*256 + threadIdx.x;
    const int n = blockIdx.y;
    if (k < K){
        unsigned short hh, hl;
        splitbf(in[(size_t)k*N + n], hh, hl);
        ohi[(size_t)n*K + k] = hh;
        olo[(size_t)n*K + k] = hl;
    }
}

__global__ __launch_bounds__(256) void k_init(float* __restrict__ sc, float* __restrict__ sv,
                                              float* __restrict__ hv32,
                                              unsigned short* __restrict__ hc0hi,
                                              unsigned short* __restrict__ hc0lo,
                                              unsigned short* __restrict__ hv0hi,
                                              unsigned short* __restrict__ hv0lo){
    const int i = blockIdx.x*256 + threadIdx.x;
    sc[i] = 0.0f; sv[i] = 0.0f; hv32[i] = 0.0f;
    hc0hi[i] = 0; hc0lo[i] = 0; hv0hi[i] = 0; hv0lo[i] = 0;
}

// ---------------------------------------------------------------------------
extern "C" void kernel_launch(void* const* d_in, const int* in_sizes, int n_in,
                              void* d_out, int out_size, void* d_ws, size_t ws_size,
                              hipStream_t stream)
{
    (void)in_sizes; (void)n_in; (void)out_size; (void)ws_size;

    const float* inputs = (const float*)d_in[0];
    const float* Wx_c   = (const float*)d_in[1];
    const float* bx_c   = (const float*)d_in[2];
    const float* Wh_c   = (const float*)d_in[3];
    const float* Wx_v   = (const float*)d_in[4];
    const float* bx_v   = (const float*)d_in[5];
    const float* Wh_v   = (const float*)d_in[6];
    const float* Ws     = (const float*)d_in[7];
    const float* Wpc0   = (const float*)d_in[8];
    const float* bpc0   = (const float*)d_in[9];
    const float* Wpc1   = (const float*)d_in[10];
    const float* bpc1   = (const float*)d_in[11];
    const float* Wfcc   = (const float*)d_in[12];
    const float* bfcc   = (const float*)d_in[13];
    const float* Wpv0   = (const float*)d_in[14];
    const float* bpv0   = (const float*)d_in[15];
    const float* Wpv1   = (const float*)d_in[16];
    const float* bpv1   = (const float*)d_in[17];
    const float* Wfcv   = (const float*)d_in[18];
    const float* bfcv   = (const float*)d_in[19];
    float* out = (float*)d_out;

    char* ws = (char*)d_ws;
    size_t off = 0;
    auto allocB = [&](size_t bytes) -> char* {
        char* p = ws + off;
        off = (off + bytes + 255) & ~(size_t)255;
        return p;
    };
    const size_t BH = (size_t)BATCH * H_DIM;
    const size_t BE = (size_t)BATCH * E_DIM;

    unsigned short* X4hi    = (unsigned short*)allocB(4*BE*2);
    unsigned short* X4lo    = (unsigned short*)allocB(4*BE*2);
    unsigned short* WcTc_hi = (unsigned short*)allocB((size_t)2048*768*2);
    unsigned short* WcTc_lo = (unsigned short*)allocB((size_t)2048*768*2);
    unsigned short* WcTv_hi = (unsigned short*)allocB((size_t)2048*768*2);
    unsigned short* WcTv_lo = (unsigned short*)allocB((size_t)2048*768*2);
    unsigned short* WsT_hi  = (unsigned short*)allocB((size_t)4*H_DIM*H_DIM*2);
    unsigned short* WsT_lo  = (unsigned short*)allocB((size_t)4*H_DIM*H_DIM*2);
    unsigned short* Wp0Tc_h = (unsigned short*)allocB((size_t)P0_DIM*H_DIM*2);
    unsigned short* Wp0Tc_l = (unsigned short*)allocB((size_t)P0_DIM*H_DIM*2);
    unsigned short* Wp0Tv_h = (unsigned short*)allocB((size_t)P0_DIM*H_DIM*2);
    unsigned short* Wp0Tv_l = (unsigned short*)allocB((size_t)P0_DIM*H_DIM*2);
    unsigned short* Wp1Tc_h = (unsigned short*)allocB((size_t)P1_DIM*P0_DIM*2);
    unsigned short* Wp1Tc_l = (unsigned short*)allocB((size_t)P1_DIM*P0_DIM*2);
    unsigned short* Wp1Tv_h = (unsigned short*)allocB((size_t)P1_DIM*P0_DIM*2);
    unsigned short* Wp1Tv_l = (unsigned short*)allocB((size_t)P1_DIM*P0_DIM*2);
    unsigned short *Hchi[2], *Hclo[2], *Hvhi[2], *Hvlo[2];
    for (int i = 0; i < 2; ++i){
        Hchi[i] = (unsigned short*)allocB(BH*2);
        Hclo[i] = (unsigned short*)allocB(BH*2);
        Hvhi[i] = (unsigned short*)allocB(BH*2);
        Hvlo[i] = (unsigned short*)allocB(BH*2);
    }
    float* sc    = (float*)allocB(BH*4);
    float* sv    = (float*)allocB(BH*4);
    float* hv32  = (float*)allocB(BH*4);
    float* gates = (float*)allocB(4*BH*4);
    float* a1    = (float*)allocB(BH*4);
    float* a2    = (float*)allocB(BH*4);
    float* g     = (float*)allocB(BATCH*4);

    const dim3 thr(256);
    const size_t HH = (size_t)H_DIM * H_DIM;

    // ---- one-time (per launch) weight conversion ----
    k_wcat<<<dim3(3, 2048), thr, 0, stream>>>(Wx_c, Wh_c, WcTc_hi, WcTc_lo);
    k_wcat<<<dim3(3, 2048), thr, 0, stream>>>(Wx_v, Wh_v, WcTv_hi, WcTv_lo);
    for (int i = 0; i < 4; ++i)
        k_trans<<<dim3(2, 512), thr, 0, stream>>>(Ws + i*HH, WsT_hi + i*HH, WsT_lo + i*HH,
                                                  H_DIM, H_DIM);
    k_trans<<<dim3(2, 256), thr, 0, stream>>>(Wpc0, Wp0Tc_h, Wp0Tc_l, H_DIM, P0_DIM);
    k_trans<<<dim3(2, 256), thr, 0, stream>>>(Wpv0, Wp0Tv_h, Wp0Tv_l, H_DIM, P0_DIM);
    k_trans<<<dim3(1, 128), thr, 0, stream>>>(Wpc1, Wp1Tc_h, Wp1Tc_l, P0_DIM, P1_DIM);
    k_trans<<<dim3(1, 128), thr, 0, stream>>>(Wpv1, Wp1Tv_h, Wp1Tv_l, P0_DIM, P1_DIM);

    // ---- init: zero states, g0 = predict_c(zeros) ----
    k_init<<<4096, thr, 0, stream>>>(sc, sv, hv32, Hchi[0], Hclo[0], Hvhi[0], Hvlo[0]);
    k_cellpred<<<128, thr, 0, stream>>>(2, gates, a1, a2, g, sc, nullptr,
                                        Hchi[1], Hclo[1],
                                        Wp0Tc_h, bpc0, Wp1Tc_h, bpc1, Wfcc, bfcc, nullptr);

    for (int t = 0; t < T_STEPS; ++t){
        const int o = t & 1, nn = o ^ 1, tq = t & 3;
        if (tq == 0)
            k_xcvt4<<<2048, thr, 0, stream>>>(inputs + (size_t)t*BE, X4hi, X4lo);
        const unsigned short* Xh = X4hi + tq*BE;
        const unsigned short* Xl = X4lo + tq*BE;

        // ---- click: gates_c + a1=Hc@Ws0 + a2=Hv@Ws1, then cell+predict ----
        k_mm<<<384, thr, 0, stream>>>(Xh, Xl, Hchi[o], Hclo[o],
                                      WcTc_hi, WcTc_lo, bx_c, gates,
                                      Hchi[o], Hclo[o], WsT_hi + 0*HH, WsT_lo + 0*HH, a1,
                                      Hvhi[o], Hvlo[o], WsT_hi + 1*HH, WsT_lo + 1*HH, a2);
        k_cellpred<<<128, thr, 0, stream>>>(0, gates, a1, a2, g, sc, nullptr,
                                            Hchi[nn], Hclo[nn],
                                            Wp0Tc_h, bpc0, Wp1Tc_h, bpc1, Wfcc, bfcc,
                                            out + (size_t)t*BATCH);

        // ---- conv: gates_v(Hc_new) + a1=Hv@Ws2 + a2=Hc_new@Ws3, cell+predict ----
        k_mm<<<384, thr, 0, stream>>>(Xh, Xl, Hchi[nn], Hclo[nn],
                                      WcTv_hi, WcTv_lo, bx_v, gates,
                                      Hvhi[o], Hvlo[o], WsT_hi + 2*HH, WsT_lo + 2*HH, a1,
                                      Hchi[nn], Hclo[nn], WsT_hi + 3*HH, WsT_lo + 3*HH, a2);
        k_cellpred<<<128, thr, 0, stream>>>(1, gates, a1, a2, g, sv, hv32,
                                            Hvhi[nn], Hvlo[nn],
                                            Wp0Tv_h, bpv0, Wp1Tv_h, bpv1, Wfcv, bfcv,
                                            out + (size_t)(T_STEPS + t)*BATCH);
    }
}

// Round 5
// 17895.659 us; speedup vs baseline: 4.7125x; 1.5018x over previous
//
#include <hip/hip_runtime.h>
#include <cstdint>
#include <cstddef>

constexpr int T_STEPS = 200;
constexpr int BATCH   = 2048;
constexpr int E_DIM   = 256;
constexpr int H_DIM   = 512;
constexpr int P0_DIM  = 256;
constexpr int P1_DIM  = 128;
constexpr float ALPHA = 0.3f;

typedef __attribute__((ext_vector_type(8))) short bf16x8;
typedef __attribute__((ext_vector_type(4))) float f32x4;

__device__ __forceinline__ float sigmoidf_(float x){ return 1.0f/(1.0f+expf(-x)); }

__device__ __forceinline__ unsigned short f2bf(float f){
    union { float f; unsigned u; } v; v.f = f;
    unsigned r = (v.u + 0x7FFFu + ((v.u >> 16) & 1u)) >> 16;   // RNE
    return (unsigned short)r;
}
__device__ __forceinline__ float bf2f(unsigned short h){
    union { unsigned u; float f; } v; v.u = ((unsigned)h) << 16; return v.f;
}
__device__ __forceinline__ void splitbf(float x, unsigned short& hi, unsigned short& lo){
    hi = f2bf(x);
    lo = f2bf(x - bf2f(hi));
}

#define GLOAD16(gp, lp) __builtin_amdgcn_global_load_lds( \
    (const __attribute__((address_space(1))) unsigned int*)(gp), \
    (__attribute__((address_space(3))) unsigned int*)(lp), 16, 0, 0)

// Stage a [ROWS][64] bf16 tile into linear LDS, slot-swizzled at the SOURCE
// (m173 pattern): LDS[r][s] holds global k-slot (s ^ (r&7)) of row r.
template<int ROWS>
__device__ __forceinline__ void stage64(const unsigned short* __restrict__ src, int ldk,
                                        char* ldsbase){
    constexpr int TOT = ROWS * 8;          // 16B slots
    const int tid = threadIdx.x;
#pragma unroll
    for (int i = 0; i < TOT/256; ++i){
        const int gsl = i*256 + tid;
        const int r = gsl >> 3, s = gsl & 7;
        const int ksrc = ((s ^ (r & 7)) << 3);
        GLOAD16(src + (size_t)r*ldk + ksrc, ldsbase + gsl*16);
    }
}

// Swizzled b128 fragment read: row-stride 128B (BK=64), kslot in [0,8).
__device__ __forceinline__ bf16x8 ldsfrag(const char* ldsbase, int row, int kslot){
    return *(const bf16x8*)(ldsbase + row*128 + ((kslot ^ (row & 7)) << 4));
}

// ---------------------------------------------------------------------------
// 128x128-tile 3-term split K-loop: acc += Ahi@B'hi + Alo@B'hi + Ahi@B'lo
// ---------------------------------------------------------------------------
__device__ __forceinline__ void mm_loop128(
    const unsigned short* __restrict__ Ahi, const unsigned short* __restrict__ Alo, int lda,
    const unsigned short* __restrict__ Bhi, const unsigned short* __restrict__ Blo, int ldb,
    int K, f32x4 (&acc)[4][4], char* lds, int wr, int wc, int lr, int lq)
{
    char* ldsAhi = lds;
    char* ldsAlo = lds + 16384;
    char* ldsBhi = lds + 32768;
    char* ldsBlo = lds + 49152;
    for (int k0 = 0; k0 < K; k0 += 64){
        stage64<128>(Ahi + k0, lda, ldsAhi);
        stage64<128>(Alo + k0, lda, ldsAlo);
        stage64<128>(Bhi + k0, ldb, ldsBhi);
        stage64<128>(Blo + k0, ldb, ldsBlo);
        __syncthreads();
#pragma unroll
        for (int kk = 0; kk < 2; ++kk){
            bf16x8 ahi[4], alo[4], bhi[4], blo[4];
#pragma unroll
            for (int m = 0; m < 4; ++m){
                ahi[m] = ldsfrag(ldsAhi, wr*64 + m*16 + lr, kk*4 + lq);
                alo[m] = ldsfrag(ldsAlo, wr*64 + m*16 + lr, kk*4 + lq);
            }
#pragma unroll
            for (int n = 0; n < 4; ++n){
                bhi[n] = ldsfrag(ldsBhi, wc*64 + n*16 + lr, kk*4 + lq);
                blo[n] = ldsfrag(ldsBlo, wc*64 + n*16 + lr, kk*4 + lq);
            }
#pragma unroll
            for (int m = 0; m < 4; ++m)
#pragma unroll
                for (int n = 0; n < 4; ++n){
                    acc[m][n] = __builtin_amdgcn_mfma_f32_16x16x32_bf16(ahi[m], bhi[n], acc[m][n], 0,0,0);
                    acc[m][n] = __builtin_amdgcn_mfma_f32_16x16x32_bf16(alo[m], bhi[n], acc[m][n], 0,0,0);
                    acc[m][n] = __builtin_amdgcn_mfma_f32_16x16x32_bf16(ahi[m], blo[n], acc[m][n], 0,0,0);
                }
        }
        __syncthreads();
    }
}

// ---------------------------------------------------------------------------
// Gates tile (id in [0,256), XCD-swizzled): gates = act(x@Wx + H@Wh + bias)
// ---------------------------------------------------------------------------
__device__ __forceinline__ void gates_tile(
    int id,
    const unsigned short* __restrict__ Xh, const unsigned short* __restrict__ Xl,
    const unsigned short* __restrict__ Hhi, const unsigned short* __restrict__ Hlo,
    const unsigned short* __restrict__ WThi, const unsigned short* __restrict__ WTlo,
    const float* __restrict__ bias, float* __restrict__ gates,
    char* lds, int wr, int wc, int lr, int lq)
{
    // XCD-bijective swizzle: XCD k gets sw in [k*32,(k+1)*32) = 2 B-panels x 16 row-tiles
    const int sw = ((id & 7) << 5) + (id >> 3);
    const int brow = (sw & 15) * 128;         // col-major tile order
    const int bcol = (sw >> 4) * 128;

    f32x4 acc[4][4];
#pragma unroll
    for (int m = 0; m < 4; ++m)
#pragma unroll
        for (int n = 0; n < 4; ++n){ f32x4 z = {0.f,0.f,0.f,0.f}; acc[m][n] = z; }

    mm_loop128(Xh  + (size_t)brow*E_DIM, Xl  + (size_t)brow*E_DIM, E_DIM,
               WThi + (size_t)bcol*768,   WTlo + (size_t)bcol*768,   768,
               E_DIM, acc, lds, wr, wc, lr, lq);
    mm_loop128(Hhi + (size_t)brow*H_DIM, Hlo + (size_t)brow*H_DIM, H_DIM,
               WThi + (size_t)bcol*768 + E_DIM, WTlo + (size_t)bcol*768 + E_DIM, 768,
               H_DIM, acc, lds, wr, wc, lr, lq);

    const int z = bcol >> 9;
    const int hbase = (bcol & 511) + wc*64;
    float* gz = gates + (size_t)z * BATCH * H_DIM;
#pragma unroll
    for (int m = 0; m < 4; ++m){
#pragma unroll
        for (int n = 0; n < 4; ++n){
            const int h = hbase + n*16 + lr;
            const float bs = bias[z*H_DIM + h];
#pragma unroll
            for (int r = 0; r < 4; ++r){
                const int b2 = brow + wr*64 + m*16 + lq*4 + r;
                float v = acc[m][n][r] + bs;
                v = (z < 3) ? sigmoidf_(v) : tanhf(v);
                gz[(size_t)b2 * H_DIM + h] = v;
            }
        }
    }
}

// ---------------------------------------------------------------------------
// Comb tile (jid in [0,64)): out = A @ B^T raw fp32 (M=2048,N=512,K=512)
// ---------------------------------------------------------------------------
__device__ __forceinline__ void comb_tile(
    int jid,
    const unsigned short* __restrict__ Ahi, const unsigned short* __restrict__ Alo,
    const unsigned short* __restrict__ Bhi, const unsigned short* __restrict__ Blo,
    float* __restrict__ outp, char* lds, int wr, int wc, int lr, int lq)
{
    const int brow = (jid >> 2) * 128, bcol = (jid & 3) * 128;
    f32x4 acc[4][4];
#pragma unroll
    for (int m = 0; m < 4; ++m)
#pragma unroll
        for (int n = 0; n < 4; ++n){ f32x4 z = {0.f,0.f,0.f,0.f}; acc[m][n] = z; }

    mm_loop128(Ahi + (size_t)brow*H_DIM, Alo + (size_t)brow*H_DIM, H_DIM,
               Bhi + (size_t)bcol*H_DIM, Blo + (size_t)bcol*H_DIM, H_DIM,
               H_DIM, acc, lds, wr, wc, lr, lq);
#pragma unroll
    for (int m = 0; m < 4; ++m){
#pragma unroll
        for (int n = 0; n < 4; ++n){
            const int h = bcol + wc*64 + n*16 + lr;
#pragma unroll
            for (int r = 0; r < 4; ++r){
                const int b2 = brow + wr*64 + m*16 + lq*4 + r;
                outp[(size_t)b2 * H_DIM + h] = acc[m][n][r];
            }
        }
    }
}

// ---------------------------------------------------------------------------
// Predict (32 rows per pblk): p0=leaky(H@W0+b0), p1=leaky(p0@W1+b1),
// val=sigmoid(dot(p1,Wf)+bf) (*gmul). Verified in round 3.
// ---------------------------------------------------------------------------
__device__ __forceinline__ void predict_dev(
    int pblk, const unsigned short* __restrict__ Hbf,
    const unsigned short* __restrict__ W0T, const float* __restrict__ b0,
    const unsigned short* __restrict__ W1T, const float* __restrict__ b1,
    const float* __restrict__ Wf, const float* __restrict__ bf_,
    float* gstate, const float* __restrict__ gmul, float* pred, char* lds)
{
    char*  ldsA = lds;                    // [32][128B]
    char*  ldsB = lds + 4096;             // up to [256][128B]
    char*  ldsP = lds + 36864;            // [32][512B] p0 bf16 (swizzled)
    float* sums = (float*)(lds + 53248);  // [4][32]
    const int tid = threadIdx.x, lane = tid & 63, w = tid >> 6;
    const int lr = lane & 15, lq = lane >> 4;
    const int brow = pblk * 32;

    f32x4 acc0[2][4];
#pragma unroll
    for (int m = 0; m < 2; ++m)
#pragma unroll
        for (int n = 0; n < 4; ++n){ f32x4 z = {0.f,0.f,0.f,0.f}; acc0[m][n] = z; }

    for (int k0 = 0; k0 < H_DIM; k0 += 64){
        stage64<32>(Hbf + (size_t)brow*H_DIM + k0, H_DIM, ldsA);
        stage64<256>(W0T + k0, H_DIM, ldsB);
        __syncthreads();
#pragma unroll
        for (int kk = 0; kk < 2; ++kk){
            bf16x8 a[2], b[4];
#pragma unroll
            for (int m = 0; m < 2; ++m) a[m] = ldsfrag(ldsA, m*16 + lr, kk*4 + lq);
#pragma unroll
            for (int n = 0; n < 4; ++n) b[n] = ldsfrag(ldsB, w*64 + n*16 + lr, kk*4 + lq);
#pragma unroll
            for (int m = 0; m < 2; ++m)
#pragma unroll
                for (int n = 0; n < 4; ++n)
                    acc0[m][n] = __builtin_amdgcn_mfma_f32_16x16x32_bf16(a[m], b[n], acc0[m][n], 0,0,0);
        }
        __syncthreads();
    }
#pragma unroll
    for (int m = 0; m < 2; ++m){
#pragma unroll
        for (int n = 0; n < 4; ++n){
            const int col = w*64 + n*16 + lr;
            const float bs = b0[col];
#pragma unroll
            for (int r = 0; r < 4; ++r){
                const int row = m*16 + lq*4 + r;
                float x = acc0[m][n][r] + bs;
                x = (x > 0.0f) ? x : ALPHA*x;
                *(unsigned short*)(ldsP + row*512 + ((((col >> 3)) ^ (row & 7)) << 4) + (col & 7)*2) = f2bf(x);
            }
        }
    }
    __syncthreads();

    f32x4 accp[2][2];
#pragma unroll
    for (int m = 0; m < 2; ++m)
#pragma unroll
        for (int n = 0; n < 2; ++n){ f32x4 z = {0.f,0.f,0.f,0.f}; accp[m][n] = z; }

    for (int k0 = 0; k0 < P0_DIM; k0 += 64){
        stage64<128>(W1T + k0, P0_DIM, ldsB);
        __syncthreads();
#pragma unroll
        for (int kk = 0; kk < 2; ++kk){
            bf16x8 a[2], b[2];
#pragma unroll
            for (int m = 0; m < 2; ++m){
                const int row = m*16 + lr;
                const int slot = (k0 >> 3) + kk*4 + lq;
                a[m] = *(const bf16x8*)(ldsP + row*512 + ((slot ^ (row & 7)) << 4));
            }
#pragma unroll
            for (int n = 0; n < 2; ++n) b[n] = ldsfrag(ldsB, w*32 + n*16 + lr, kk*4 + lq);
#pragma unroll
            for (int m = 0; m < 2; ++m)
#pragma unroll
                for (int n = 0; n < 2; ++n)
                    accp[m][n] = __builtin_amdgcn_mfma_f32_16x16x32_bf16(a[m], b[n], accp[m][n], 0,0,0);
        }
        __syncthreads();
    }

    float part[8];
#pragma unroll
    for (int j = 0; j < 8; ++j) part[j] = 0.0f;
#pragma unroll
    for (int m = 0; m < 2; ++m){
#pragma unroll
        for (int n = 0; n < 2; ++n){
            const int col = w*32 + n*16 + lr;
            const float bs = b1[col], wf = Wf[col];
#pragma unroll
            for (int r = 0; r < 4; ++r){
                float x = accp[m][n][r] + bs;
                x = (x > 0.0f) ? x : ALPHA*x;
                part[m*4 + r] += x * wf;
            }
        }
    }
#pragma unroll
    for (int mask = 1; mask < 16; mask <<= 1)
#pragma unroll
        for (int j = 0; j < 8; ++j) part[j] += __shfl_xor(part[j], mask);
    if (lr == 0){
#pragma unroll
        for (int j = 0; j < 8; ++j){
            const int row = (j >> 2)*16 + lq*4 + (j & 3);
            sums[w*32 + row] = part[j];
        }
    }
    __syncthreads();
    if (tid < 32){
        float tot = sums[tid] + sums[32 + tid] + sums[64 + tid] + sums[96 + tid] + bf_[0];
        float val = sigmoidf_(tot);
        const int rowg = brow + tid;
        if (gmul)   val *= gmul[rowg];
        if (gstate) gstate[rowg] = val;
        if (pred)   pred[rowg]   = val;
    }
}

// x-step bf16 split-convert: 128 blocks x 256 thr x 4 float4.
__device__ __forceinline__ void xcvt_dev(int blk, const float* __restrict__ x,
                                         unsigned short* __restrict__ ohi,
                                         unsigned short* __restrict__ olo)
{
    const int tid = threadIdx.x;
#pragma unroll
    for (int j = 0; j < 4; ++j){
        const int t = blk*256 + tid + j*32768;
        float4 v = ((const float4*)x)[t];
        ushort4 h, l;
        splitbf(v.x, h.x, l.x); splitbf(v.y, h.y, l.y);
        splitbf(v.z, h.z, l.z); splitbf(v.w, h.w, l.w);
        ((ushort4*)ohi)[t] = h;
        ((ushort4*)olo)[t] = l;
    }
}

// ---------------------------------------------------------------------------
// mmA: [0,256) gates_c | [256,448) comb a1_c/a2_c/a1_v | [448,512) predict_v(t-1)
// ---------------------------------------------------------------------------
__global__ __launch_bounds__(256, 2) void k_mmA(
    const unsigned short* __restrict__ Xh,  const unsigned short* __restrict__ Xl,
    const unsigned short* __restrict__ Hchi, const unsigned short* __restrict__ Hclo,
    const unsigned short* __restrict__ Hvhi, const unsigned short* __restrict__ Hvlo,
    const unsigned short* __restrict__ WThi, const unsigned short* __restrict__ WTlo,
    const float* __restrict__ bias, float* __restrict__ gates,
    const unsigned short* __restrict__ Ws0hi, const unsigned short* __restrict__ Ws0lo,
    float* __restrict__ a1,
    const unsigned short* __restrict__ Ws1hi, const unsigned short* __restrict__ Ws1lo,
    float* __restrict__ a2,
    const unsigned short* __restrict__ Ws2hi, const unsigned short* __restrict__ Ws2lo,
    float* __restrict__ a1v,
    const unsigned short* __restrict__ W0Tv, const float* __restrict__ b0v,
    const unsigned short* __restrict__ W1Tv, const float* __restrict__ b1v,
    const float* __restrict__ Wfv, const float* __restrict__ bfv,
    const float* __restrict__ g, float* __restrict__ predv)
{
    __shared__ __align__(16) char lds[65536];
    const int tid = threadIdx.x;
    const int lane = tid & 63, wid = tid >> 6;
    const int wr = wid >> 1, wc = wid & 1;
    const int lr = lane & 15, lq = lane >> 4;
    const int id = blockIdx.x;

    if (id < 256){
        gates_tile(id, Xh, Xl, Hchi, Hclo, WThi, WTlo, bias, gates, lds, wr, wc, lr, lq);
    } else if (id < 448){
        const int j = (id - 256) >> 6, jid = (id - 256) & 63;
        if (j == 0)      comb_tile(jid, Hchi, Hclo, Ws0hi, Ws0lo, a1,  lds, wr, wc, lr, lq);
        else if (j == 1) comb_tile(jid, Hvhi, Hvlo, Ws1hi, Ws1lo, a2,  lds, wr, wc, lr, lq);
        else             comb_tile(jid, Hvhi, Hvlo, Ws2hi, Ws2lo, a1v, lds, wr, wc, lr, lq);
    } else {
        predict_dev(id - 448, Hvhi, W0Tv, b0v, W1Tv, b1v, Wfv, bfv,
                    nullptr, g, predv, lds);
    }
}

// ---------------------------------------------------------------------------
// mmB: [0,256) gates_v | [256,320) a2_v | [320,384) predict_c | [384,512) xcvt(t+1)
// ---------------------------------------------------------------------------
__global__ __launch_bounds__(256, 2) void k_mmB(
    const unsigned short* __restrict__ Xh,  const unsigned short* __restrict__ Xl,
    const unsigned short* __restrict__ Hchi, const unsigned short* __restrict__ Hclo,
    const unsigned short* __restrict__ WThi, const unsigned short* __restrict__ WTlo,
    const float* __restrict__ bias, float* __restrict__ gates,
    const unsigned short* __restrict__ Ws3hi, const unsigned short* __restrict__ Ws3lo,
    float* __restrict__ a2v,
    const unsigned short* __restrict__ W0Tc, const float* __restrict__ b0c,
    const unsigned short* __restrict__ W1Tc, const float* __restrict__ b1c,
    const float* __restrict__ Wfc, const float* __restrict__ bfc,
    float* __restrict__ g, float* __restrict__ predc,
    const float* __restrict__ xnext, unsigned short* __restrict__ Xnh,
    unsigned short* __restrict__ Xnl)
{
    __shared__ __align__(16) char lds[65536];
    const int tid = threadIdx.x;
    const int lane = tid & 63, wid = tid >> 6;
    const int wr = wid >> 1, wc = wid & 1;
    const int lr = lane & 15, lq = lane >> 4;
    const int id = blockIdx.x;

    if (id < 256){
        gates_tile(id, Xh, Xl, Hchi, Hclo, WThi, WTlo, bias, gates, lds, wr, wc, lr, lq);
    } else if (id < 320){
        comb_tile(id - 256, Hchi, Hclo, Ws3hi, Ws3lo, a2v, lds, wr, wc, lr, lq);
    } else if (id < 384){
        predict_dev(id - 320, Hchi, W0Tc, b0c, W1Tc, b1c, Wfc, bfc,
                    g, nullptr, predc, lds);
    } else {
        xcvt_dev(id - 384, xnext, Xnh, Xnl);
    }
}

// ---------------------------------------------------------------------------
// Cell elementwise update: 1024 blocks x 256 thr x 4 elems.
// mode 0 (click): s=tanh((1-g)a1+g*a2)+i*q+(1-g)*f*s; H=o*tanh(s)
// mode 1 (conv):  s=tanh(a1+g*a2)+(1-g)*s+g*(f*s+i*q); H=(1-g)*Hv32+g*o*tanh(s)
// ---------------------------------------------------------------------------
__global__ __launch_bounds__(256) void k_cell(
    const int mode, const float* __restrict__ gates, const float* __restrict__ a1,
    const float* __restrict__ a2, const float* __restrict__ g,
    float* __restrict__ sstate, float* __restrict__ Hv32,
    unsigned short* __restrict__ Outhi, unsigned short* __restrict__ Outlo)
{
    const size_t BH = (size_t)BATCH * H_DIM;
    const int i4 = blockIdx.x*256 + threadIdx.x;
    const size_t base = (size_t)i4 * 4;
    const int row = (int)(base >> 9);
    const float gv = g[row];
    union U4 { float4 v; float s[4]; };
    U4 f_, i_, o_, q_, u1, u2, sv, hv;
    f_.v = *(const float4*)&gates[base];
    i_.v = *(const float4*)&gates[BH + base];
    o_.v = *(const float4*)&gates[2*BH + base];
    q_.v = *(const float4*)&gates[3*BH + base];
    u1.v = *(const float4*)&a1[base];
    u2.v = *(const float4*)&a2[base];
    sv.v = *(const float4*)&sstate[base];
    if (mode == 1) hv.v = *(const float4*)&Hv32[base];
    U4 sn;
    union { unsigned short u[4]; ushort4 v; } hh, hl;
    U4 hnew;
#pragma unroll
    for (int e = 0; e < 4; ++e){
        float hval, s;
        if (mode == 0){
            const float shat = tanhf((1.0f - gv)*u1.s[e] + gv*u2.s[e]);
            s = shat + i_.s[e]*q_.s[e] + (1.0f - gv)*(f_.s[e]*sv.s[e]);
            hval = o_.s[e] * tanhf(s);
        } else {
            const float shat = tanhf(u1.s[e] + gv*u2.s[e]);
            const float svo = sv.s[e];
            s = shat + (1.0f - gv)*svo + gv*(f_.s[e]*svo + i_.s[e]*q_.s[e]);
            hval = (1.0f - gv)*hv.s[e] + gv*(o_.s[e]*tanhf(s));
            hnew.s[e] = hval;
        }
        sn.s[e] = s;
        splitbf(hval, hh.u[e], hl.u[e]);
    }
    *(float4*)&sstate[base] = sn.v;
    if (mode == 1) *(float4*)&Hv32[base] = hnew.v;
    *(ushort4*)&Outhi[base] = hh.v;
    *(ushort4*)&Outlo[base] = hl.v;
}

// ---------------------------------------------------------------------------
// Standalone predict (init g0 / final pred_v) and x0 convert.
// ---------------------------------------------------------------------------
__global__ __launch_bounds__(256) void k_predict_g(
    const unsigned short* __restrict__ Hbf,
    const unsigned short* __restrict__ W0T, const float* __restrict__ b0,
    const unsigned short* __restrict__ W1T, const float* __restrict__ b1,
    const float* __restrict__ Wf, const float* __restrict__ bf_,
    float* gstate, const float* __restrict__ gmul, float* pred)
{
    __shared__ __align__(16) char lds[53760];
    predict_dev(blockIdx.x, Hbf, W0T, b0, W1T, b1, Wf, bf_, gstate, gmul, pred, lds);
}

__global__ __launch_bounds__(256) void k_xcvt_g(const float* __restrict__ x,
                                                unsigned short* __restrict__ ohi,
                                                unsigned short* __restrict__ olo)
{
    xcvt_dev(blockIdx.x, x, ohi, olo);
}

// ---------------------------------------------------------------------------
// Prep kernels
// ---------------------------------------------------------------------------
__global__ __launch_bounds__(256) void k_wcat(const float* __restrict__ Wx,
                                              const float* __restrict__ Wh,
                                              unsigned short* __restrict__ ohi,
                                              unsigned short* __restrict__ olo){
    const int n = blockIdx.y;
    const int k = blockIdx.x*256 + threadIdx.x;
    const int z = n >> 9, h = n & 511;
    float v = (k < 256) ? Wx[((size_t)z*E_DIM + k)*H_DIM + h]
                        : Wh[((size_t)z*H_DIM + (k - 256))*H_DIM + h];
    unsigned short hh, hl;
    splitbf(v, hh, hl);
    ohi[(size_t)n*768 + k] = hh;
    olo[(size_t)n*768 + k] = hl;
}

__global__ __launch_bounds__(256) void k_trans(const float* __restrict__ in,
                                               unsigned short* __restrict__ ohi,
                                               unsigned short* __restrict__ olo,
                                               int K, int N){
    const int k = blockIdx.x*256 + threadIdx.x;
    const int n = blockIdx.y;
    if (k < K){
        unsigned short hh, hl;
        splitbf(in[(size_t)k*N + n], hh, hl);
        ohi[(size_t)n*K + k] = hh;
        olo[(size_t)n*K + k] = hl;
    }
}

__global__ __launch_bounds__(256) void k_init(float* __restrict__ sc, float* __restrict__ sv,
                                              float* __restrict__ hv32,
                                              unsigned short* __restrict__ hc0hi,
                                              unsigned short* __restrict__ hc0lo,
                                              unsigned short* __restrict__ hv0hi,
                                              unsigned short* __restrict__ hv0lo){
    const int i = blockIdx.x*256 + threadIdx.x;
    sc[i] = 0.0f; sv[i] = 0.0f; hv32[i] = 0.0f;
    hc0hi[i] = 0; hc0lo[i] = 0; hv0hi[i] = 0; hv0lo[i] = 0;
}

// ---------------------------------------------------------------------------
extern "C" void kernel_launch(void* const* d_in, const int* in_sizes, int n_in,
                              void* d_out, int out_size, void* d_ws, size_t ws_size,
                              hipStream_t stream)
{
    (void)in_sizes; (void)n_in; (void)out_size; (void)ws_size;

    const float* inputs = (const float*)d_in[0];
    const float* Wx_c   = (const float*)d_in[1];
    const float* bx_c   = (const float*)d_in[2];
    const float* Wh_c   = (const float*)d_in[3];
    const float* Wx_v   = (const float*)d_in[4];
    const float* bx_v   = (const float*)d_in[5];
    const float* Wh_v   = (const float*)d_in[6];
    const float* Ws     = (const float*)d_in[7];
    const float* Wpc0   = (const float*)d_in[8];
    const float* bpc0   = (const float*)d_in[9];
    const float* Wpc1   = (const float*)d_in[10];
    const float* bpc1   = (const float*)d_in[11];
    const float* Wfcc   = (const float*)d_in[12];
    const float* bfcc   = (const float*)d_in[13];
    const float* Wpv0   = (const float*)d_in[14];
    const float* bpv0   = (const float*)d_in[15];
    const float* Wpv1   = (const float*)d_in[16];
    const float* bpv1   = (const float*)d_in[17];
    const float* Wfcv   = (const float*)d_in[18];
    const float* bfcv   = (const float*)d_in[19];
    float* out = (float*)d_out;

    char* ws = (char*)d_ws;
    size_t off = 0;
    auto allocB = [&](size_t bytes) -> char* {
        char* p = ws + off;
        off = (off + bytes + 255) & ~(size_t)255;
        return p;
    };
    const size_t BH = (size_t)BATCH * H_DIM;
    const size_t BE = (size_t)BATCH * E_DIM;

    unsigned short* Xhi[2], *Xlo[2];
    for (int i = 0; i < 2; ++i){
        Xhi[i] = (unsigned short*)allocB(BE*2);
        Xlo[i] = (unsigned short*)allocB(BE*2);
    }
    unsigned short* WcTc_hi = (unsigned short*)allocB((size_t)2048*768*2);
    unsigned short* WcTc_lo = (unsigned short*)allocB((size_t)2048*768*2);
    unsigned short* WcTv_hi = (unsigned short*)allocB((size_t)2048*768*2);
    unsigned short* WcTv_lo = (unsigned short*)allocB((size_t)2048*768*2);
    unsigned short* WsT_hi  = (unsigned short*)allocB((size_t)4*H_DIM*H_DIM*2);
    unsigned short* WsT_lo  = (unsigned short*)allocB((size_t)4*H_DIM*H_DIM*2);
    unsigned short* Wp0Tc_h = (unsigned short*)allocB((size_t)P0_DIM*H_DIM*2);
    unsigned short* Wp0Tc_l = (unsigned short*)allocB((size_t)P0_DIM*H_DIM*2);
    unsigned short* Wp0Tv_h = (unsigned short*)allocB((size_t)P0_DIM*H_DIM*2);
    unsigned short* Wp0Tv_l = (unsigned short*)allocB((size_t)P0_DIM*H_DIM*2);
    unsigned short* Wp1Tc_h = (unsigned short*)allocB((size_t)P1_DIM*P0_DIM*2);
    unsigned short* Wp1Tc_l = (unsigned short*)allocB((size_t)P1_DIM*P0_DIM*2);
    unsigned short* Wp1Tv_h = (unsigned short*)allocB((size_t)P1_DIM*P0_DIM*2);
    unsigned short* Wp1Tv_l = (unsigned short*)allocB((size_t)P1_DIM*P0_DIM*2);
    unsigned short* Hchi = (unsigned short*)allocB(BH*2);
    unsigned short* Hclo = (unsigned short*)allocB(BH*2);
    unsigned short* Hvhi = (unsigned short*)allocB(BH*2);
    unsigned short* Hvlo = (unsigned short*)allocB(BH*2);
    float* sc    = (float*)allocB(BH*4);
    float* sv    = (float*)allocB(BH*4);
    float* hv32  = (float*)allocB(BH*4);
    float* gates = (float*)allocB(4*BH*4);
    float* a1    = (float*)allocB(BH*4);
    float* a2    = (float*)allocB(BH*4);
    float* a1v   = (float*)allocB(BH*4);
    float* a2v   = (float*)allocB(BH*4);
    float* g     = (float*)allocB(BATCH*4);

    const dim3 thr(256);
    const size_t HH = (size_t)H_DIM * H_DIM;

    // ---- one-time weight conversion ----
    k_wcat<<<dim3(3, 2048), thr, 0, stream>>>(Wx_c, Wh_c, WcTc_hi, WcTc_lo);
    k_wcat<<<dim3(3, 2048), thr, 0, stream>>>(Wx_v, Wh_v, WcTv_hi, WcTv_lo);
    for (int i = 0; i < 4; ++i)
        k_trans<<<dim3(2, 512), thr, 0, stream>>>(Ws + i*HH, WsT_hi + i*HH, WsT_lo + i*HH,
                                                  H_DIM, H_DIM);
    k_trans<<<dim3(2, 256), thr, 0, stream>>>(Wpc0, Wp0Tc_h, Wp0Tc_l, H_DIM, P0_DIM);
    k_trans<<<dim3(2, 256), thr, 0, stream>>>(Wpv0, Wp0Tv_h, Wp0Tv_l, H_DIM, P0_DIM);
    k_trans<<<dim3(1, 128), thr, 0, stream>>>(Wpc1, Wp1Tc_h, Wp1Tc_l, P0_DIM, P1_DIM);
    k_trans<<<dim3(1, 128), thr, 0, stream>>>(Wpv1, Wp1Tv_h, Wp1Tv_l, P0_DIM, P1_DIM);

    // ---- init: zero states; g0 = predict_c(zeros); convert x(0) ----
    k_init<<<4096, thr, 0, stream>>>(sc, sv, hv32, Hchi, Hclo, Hvhi, Hvlo);
    k_predict_g<<<64, thr, 0, stream>>>(Hchi, Wp0Tc_h, bpc0, Wp1Tc_h, bpc1, Wfcc, bfcc,
                                        g, nullptr, nullptr);
    k_xcvt_g<<<128, thr, 0, stream>>>(inputs, Xhi[0], Xlo[0]);

    for (int t = 0; t < T_STEPS; ++t){
        const int xs = t & 1, xn = xs ^ 1;
        const unsigned short* Xh = Xhi[xs];
        const unsigned short* Xl = Xlo[xs];

        // mmA: gates_c + a1_c + a2_c + a1_v (+ predict_v(t-1) when t>0)
        const int gridA = (t > 0) ? 512 : 448;
        k_mmA<<<gridA, thr, 0, stream>>>(Xh, Xl, Hchi, Hclo, Hvhi, Hvlo,
                                         WcTc_hi, WcTc_lo, bx_c, gates,
                                         WsT_hi + 0*HH, WsT_lo + 0*HH, a1,
                                         WsT_hi + 1*HH, WsT_lo + 1*HH, a2,
                                         WsT_hi + 2*HH, WsT_lo + 2*HH, a1v,
                                         Wp0Tv_h, bpv0, Wp1Tv_h, bpv1, Wfcv, bfcv,
                                         g, out + (size_t)(T_STEPS + t - 1)*BATCH);
        // cell_c -> Hc_new, sc
        k_cell<<<1024, thr, 0, stream>>>(0, gates, a1, a2, g, sc, nullptr, Hchi, Hclo);

        // mmB: gates_v(Hc_new) + a2_v + predict_c (+ xcvt(t+1))
        const int gridB = (t + 1 < T_STEPS) ? 512 : 384;
        k_mmB<<<gridB, thr, 0, stream>>>(Xh, Xl, Hchi, Hclo,
                                         WcTv_hi, WcTv_lo, bx_v, gates,
                                         WsT_hi + 3*HH, WsT_lo + 3*HH, a2v,
                                         Wp0Tc_h, bpc0, Wp1Tc_h, bpc1, Wfcc, bfcc,
                                         g, out + (size_t)t*BATCH,
                                         inputs + (size_t)(t+1)*BE, Xhi[xn], Xlo[xn]);
        // cell_v -> Hv_new, sv, hv32
        k_cell<<<1024, thr, 0, stream>>>(1, gates, a1v, a2v, g, sv, hv32, Hvhi, Hvlo);
    }
    // final pred_v(T-1)
    k_predict_g<<<64, thr, 0, stream>>>(Hvhi, Wp0Tv_h, bpv0, Wp1Tv_h, bpv1, Wfcv, bfcv,
                                        nullptr, g, out + (size_t)(2*T_STEPS - 1)*BATCH);
}

// Round 6
// 12165.018 us; speedup vs baseline: 6.9325x; 1.4711x over previous
//
#include <hip/hip_runtime.h>
#include <cstdint>
#include <cstddef>

constexpr int T_STEPS = 200;
constexpr int BATCH   = 2048;
constexpr int E_DIM   = 256;
constexpr int H_DIM   = 512;
constexpr int P0_DIM  = 256;
constexpr int P1_DIM  = 128;
constexpr float ALPHA = 0.3f;

typedef __attribute__((ext_vector_type(8))) _Float16 f16x8;
typedef __attribute__((ext_vector_type(4))) float f32x4;

__device__ __forceinline__ float sigmoidf_(float x){ return 1.0f/(1.0f+expf(-x)); }

__device__ __forceinline__ unsigned short f2h(float f){
    union { _Float16 h; unsigned short u; } v;
    v.h = (_Float16)f;                 // v_cvt_f16_f32, RNE
    return v.u;
}

#define GLOAD16(gp, lp) __builtin_amdgcn_global_load_lds( \
    (const __attribute__((address_space(1))) unsigned int*)(gp), \
    (__attribute__((address_space(3))) unsigned int*)(lp), 16, 0, 0)

// Stage a [ROWS][64] 16-bit tile into linear LDS, slot-swizzled at the SOURCE
// (m173 pattern): LDS[r][s] holds global k-slot (s ^ (r&7)) of row r.
template<int ROWS>
__device__ __forceinline__ void stage64(const unsigned short* __restrict__ src, int ldk,
                                        char* ldsbase){
    constexpr int TOT = ROWS * 8;          // 16B slots
    const int tid = threadIdx.x;
#pragma unroll
    for (int i = 0; i < TOT/256; ++i){
        const int gsl = i*256 + tid;
        const int r = gsl >> 3, s = gsl & 7;
        const int ksrc = ((s ^ (r & 7)) << 3);
        GLOAD16(src + (size_t)r*ldk + ksrc, ldsbase + gsl*16);
    }
}

// Swizzled b128 fragment read: row-stride 128B (BK=64), kslot in [0,8).
__device__ __forceinline__ f16x8 ldsfragh(const char* ldsbase, int row, int kslot){
    return *(const f16x8*)(ldsbase + row*128 + ((kslot ^ (row & 7)) << 4));
}

// ---------------------------------------------------------------------------
// 128x128-tile fp16 K-loop, 2-phase double-buffered staging:
// issue STAGE(slab k+1) -> compute slab k -> barrier (drains both).
// LDS: buf b at lds + b*32768  (A at +0, B at +16384).
// ---------------------------------------------------------------------------
__device__ __forceinline__ void mm_loop128h(
    const unsigned short* __restrict__ A, int lda,
    const unsigned short* __restrict__ B, int ldb,
    int K, f32x4 (&acc)[4][4], char* lds, int wr, int wc, int lr, int lq)
{
    stage64<128>(A, lda, lds);
    stage64<128>(B, ldb, lds + 16384);
    __syncthreads();
    int cur = 0;
    for (int k0 = 0; k0 < K; k0 += 64){
        char* bufc = lds + cur*32768;
        if (k0 + 64 < K){
            char* bufn = lds + (cur^1)*32768;
            stage64<128>(A + k0 + 64, lda, bufn);
            stage64<128>(B + k0 + 64, ldb, bufn + 16384);
        }
#pragma unroll
        for (int kk = 0; kk < 2; ++kk){
            f16x8 a[4], b[4];
#pragma unroll
            for (int m = 0; m < 4; ++m) a[m] = ldsfragh(bufc, wr*64 + m*16 + lr, kk*4 + lq);
#pragma unroll
            for (int n = 0; n < 4; ++n) b[n] = ldsfragh(bufc + 16384, wc*64 + n*16 + lr, kk*4 + lq);
#pragma unroll
            for (int m = 0; m < 4; ++m)
#pragma unroll
                for (int n = 0; n < 4; ++n)
                    acc[m][n] = __builtin_amdgcn_mfma_f32_16x16x32_f16(a[m], b[n], acc[m][n], 0,0,0);
        }
        __syncthreads();
        cur ^= 1;
    }
}

// ---------------------------------------------------------------------------
// Gates tile (id in [0,256), XCD-swizzled): gates = act(x@Wx + H@Wh + bias)
// ---------------------------------------------------------------------------
__device__ __forceinline__ void gates_tile(
    int id,
    const unsigned short* __restrict__ Xh,
    const unsigned short* __restrict__ Hh,
    const unsigned short* __restrict__ WT,
    const float* __restrict__ bias, float* __restrict__ gates,
    char* lds, int wr, int wc, int lr, int lq)
{
    // XCD-bijective swizzle: XCD k gets sw in [k*32,(k+1)*32) = 2 B-panels x 16 row-tiles
    const int sw = ((id & 7) << 5) + (id >> 3);
    const int brow = (sw & 15) * 128;         // col-major tile order
    const int bcol = (sw >> 4) * 128;

    f32x4 acc[4][4];
#pragma unroll
    for (int m = 0; m < 4; ++m)
#pragma unroll
        for (int n = 0; n < 4; ++n){ f32x4 z = {0.f,0.f,0.f,0.f}; acc[m][n] = z; }

    mm_loop128h(Xh + (size_t)brow*E_DIM, E_DIM,
                WT + (size_t)bcol*768, 768,
                E_DIM, acc, lds, wr, wc, lr, lq);
    mm_loop128h(Hh + (size_t)brow*H_DIM, H_DIM,
                WT + (size_t)bcol*768 + E_DIM, 768,
                H_DIM, acc, lds, wr, wc, lr, lq);

    const int z = bcol >> 9;
    const int hbase = (bcol & 511) + wc*64;
    float* gz = gates + (size_t)z * BATCH * H_DIM;
#pragma unroll
    for (int m = 0; m < 4; ++m){
#pragma unroll
        for (int n = 0; n < 4; ++n){
            const int h = hbase + n*16 + lr;
            const float bs = bias[z*H_DIM + h];
#pragma unroll
            for (int r = 0; r < 4; ++r){
                const int b2 = brow + wr*64 + m*16 + lq*4 + r;
                float v = acc[m][n][r] + bs;
                v = (z < 3) ? sigmoidf_(v) : tanhf(v);
                gz[(size_t)b2 * H_DIM + h] = v;
            }
        }
    }
}

// ---------------------------------------------------------------------------
// Comb tile (jid in [0,64)): out = A @ B^T raw fp32 (M=2048,N=512,K=512)
// ---------------------------------------------------------------------------
__device__ __forceinline__ void comb_tile(
    int jid,
    const unsigned short* __restrict__ A,
    const unsigned short* __restrict__ B,
    float* __restrict__ outp, char* lds, int wr, int wc, int lr, int lq)
{
    const int brow = (jid >> 2) * 128, bcol = (jid & 3) * 128;
    f32x4 acc[4][4];
#pragma unroll
    for (int m = 0; m < 4; ++m)
#pragma unroll
        for (int n = 0; n < 4; ++n){ f32x4 z = {0.f,0.f,0.f,0.f}; acc[m][n] = z; }

    mm_loop128h(A + (size_t)brow*H_DIM, H_DIM,
                B + (size_t)bcol*H_DIM, H_DIM,
                H_DIM, acc, lds, wr, wc, lr, lq);
#pragma unroll
    for (int m = 0; m < 4; ++m){
#pragma unroll
        for (int n = 0; n < 4; ++n){
            const int h = bcol + wc*64 + n*16 + lr;
#pragma unroll
            for (int r = 0; r < 4; ++r){
                const int b2 = brow + wr*64 + m*16 + lq*4 + r;
                outp[(size_t)b2 * H_DIM + h] = acc[m][n][r];
            }
        }
    }
}

// ---------------------------------------------------------------------------
// Predict (32 rows per pblk): p0=leaky(H@W0+b0), p1=leaky(p0@W1+b1),
// val=sigmoid(dot(p1,Wf)+bf) (*gmul). fp16 operands, fp32 accum.
// ---------------------------------------------------------------------------
__device__ __forceinline__ void predict_dev(
    int pblk, const unsigned short* __restrict__ Hh,
    const unsigned short* __restrict__ W0T, const float* __restrict__ b0,
    const unsigned short* __restrict__ W1T, const float* __restrict__ b1,
    const float* __restrict__ Wf, const float* __restrict__ bf_,
    float* gstate, const float* __restrict__ gmul, float* pred, char* lds)
{
    char*  ldsA = lds;                    // [32][128B]
    char*  ldsB = lds + 4096;             // up to [256][128B]
    char*  ldsP = lds + 36864;            // [32][512B] p0 fp16 (swizzled)
    float* sums = (float*)(lds + 53248);  // [4][32]
    const int tid = threadIdx.x, lane = tid & 63, w = tid >> 6;
    const int lr = lane & 15, lq = lane >> 4;
    const int brow = pblk * 32;

    f32x4 acc0[2][4];
#pragma unroll
    for (int m = 0; m < 2; ++m)
#pragma unroll
        for (int n = 0; n < 4; ++n){ f32x4 z = {0.f,0.f,0.f,0.f}; acc0[m][n] = z; }

    for (int k0 = 0; k0 < H_DIM; k0 += 64){
        stage64<32>(Hh + (size_t)brow*H_DIM + k0, H_DIM, ldsA);
        stage64<256>(W0T + k0, H_DIM, ldsB);
        __syncthreads();
#pragma unroll
        for (int kk = 0; kk < 2; ++kk){
            f16x8 a[2], b[4];
#pragma unroll
            for (int m = 0; m < 2; ++m) a[m] = ldsfragh(ldsA, m*16 + lr, kk*4 + lq);
#pragma unroll
            for (int n = 0; n < 4; ++n) b[n] = ldsfragh(ldsB, w*64 + n*16 + lr, kk*4 + lq);
#pragma unroll
            for (int m = 0; m < 2; ++m)
#pragma unroll
                for (int n = 0; n < 4; ++n)
                    acc0[m][n] = __builtin_amdgcn_mfma_f32_16x16x32_f16(a[m], b[n], acc0[m][n], 0,0,0);
        }
        __syncthreads();
    }
#pragma unroll
    for (int m = 0; m < 2; ++m){
#pragma unroll
        for (int n = 0; n < 4; ++n){
            const int col = w*64 + n*16 + lr;
            const float bs = b0[col];
#pragma unroll
            for (int r = 0; r < 4; ++r){
                const int row = m*16 + lq*4 + r;
                float x = acc0[m][n][r] + bs;
                x = (x > 0.0f) ? x : ALPHA*x;
                *(unsigned short*)(ldsP + row*512 + ((((col >> 3)) ^ (row & 7)) << 4) + (col & 7)*2) = f2h(x);
            }
        }
    }
    __syncthreads();

    f32x4 accp[2][2];
#pragma unroll
    for (int m = 0; m < 2; ++m)
#pragma unroll
        for (int n = 0; n < 2; ++n){ f32x4 z = {0.f,0.f,0.f,0.f}; accp[m][n] = z; }

    for (int k0 = 0; k0 < P0_DIM; k0 += 64){
        stage64<128>(W1T + k0, P0_DIM, ldsB);
        __syncthreads();
#pragma unroll
        for (int kk = 0; kk < 2; ++kk){
            f16x8 a[2], b[2];
#pragma unroll
            for (int m = 0; m < 2; ++m){
                const int row = m*16 + lr;
                const int slot = (k0 >> 3) + kk*4 + lq;
                a[m] = *(const f16x8*)(ldsP + row*512 + ((slot ^ (row & 7)) << 4));
            }
#pragma unroll
            for (int n = 0; n < 2; ++n) b[n] = ldsfragh(ldsB, w*32 + n*16 + lr, kk*4 + lq);
#pragma unroll
            for (int m = 0; m < 2; ++m)
#pragma unroll
                for (int n = 0; n < 2; ++n)
                    accp[m][n] = __builtin_amdgcn_mfma_f32_16x16x32_f16(a[m], b[n], accp[m][n], 0,0,0);
        }
        __syncthreads();
    }

    float part[8];
#pragma unroll
    for (int j = 0; j < 8; ++j) part[j] = 0.0f;
#pragma unroll
    for (int m = 0; m < 2; ++m){
#pragma unroll
        for (int n = 0; n < 2; ++n){
            const int col = w*32 + n*16 + lr;
            const float bs = b1[col], wf = Wf[col];
#pragma unroll
            for (int r = 0; r < 4; ++r){
                float x = accp[m][n][r] + bs;
                x = (x > 0.0f) ? x : ALPHA*x;
                part[m*4 + r] += x * wf;
            }
        }
    }
#pragma unroll
    for (int mask = 1; mask < 16; mask <<= 1)
#pragma unroll
        for (int j = 0; j < 8; ++j) part[j] += __shfl_xor(part[j], mask);
    if (lr == 0){
#pragma unroll
        for (int j = 0; j < 8; ++j){
            const int row = (j >> 2)*16 + lq*4 + (j & 3);
            sums[w*32 + row] = part[j];
        }
    }
    __syncthreads();
    if (tid < 32){
        float tot = sums[tid] + sums[32 + tid] + sums[64 + tid] + sums[96 + tid] + bf_[0];
        float val = sigmoidf_(tot);
        const int rowg = brow + tid;
        if (gmul)   val *= gmul[rowg];
        if (gstate) gstate[rowg] = val;
        if (pred)   pred[rowg]   = val;
    }
}

// x-step fp16 convert: 128 blocks x 256 thr x 4 float4.
__device__ __forceinline__ void xcvt_dev(int blk, const float* __restrict__ x,
                                         unsigned short* __restrict__ oh)
{
    const int tid = threadIdx.x;
#pragma unroll
    for (int j = 0; j < 4; ++j){
        const int t = blk*256 + tid + j*32768;
        float4 v = ((const float4*)x)[t];
        ushort4 h;
        h.x = f2h(v.x); h.y = f2h(v.y); h.z = f2h(v.z); h.w = f2h(v.w);
        ((ushort4*)oh)[t] = h;
    }
}

// ---------------------------------------------------------------------------
// mmA: [0,256) gates_c | [256,448) comb a1_c/a2_c/a1_v | [448,512) predict_v(t-1)
// ---------------------------------------------------------------------------
__global__ __launch_bounds__(256, 2) void k_mmA(
    const unsigned short* __restrict__ Xh,
    const unsigned short* __restrict__ Hc, const unsigned short* __restrict__ Hv,
    const unsigned short* __restrict__ WT,
    const float* __restrict__ bias, float* __restrict__ gates,
    const unsigned short* __restrict__ Ws0, float* __restrict__ a1,
    const unsigned short* __restrict__ Ws1, float* __restrict__ a2,
    const unsigned short* __restrict__ Ws2, float* __restrict__ a1v,
    const unsigned short* __restrict__ W0Tv, const float* __restrict__ b0v,
    const unsigned short* __restrict__ W1Tv, const float* __restrict__ b1v,
    const float* __restrict__ Wfv, const float* __restrict__ bfv,
    const float* __restrict__ g, float* __restrict__ predv)
{
    __shared__ __align__(16) char lds[65536];
    const int tid = threadIdx.x;
    const int lane = tid & 63, wid = tid >> 6;
    const int wr = wid >> 1, wc = wid & 1;
    const int lr = lane & 15, lq = lane >> 4;
    const int id = blockIdx.x;

    if (id < 256){
        gates_tile(id, Xh, Hc, WT, bias, gates, lds, wr, wc, lr, lq);
    } else if (id < 448){
        const int j = (id - 256) >> 6, jid = (id - 256) & 63;
        if (j == 0)      comb_tile(jid, Hc, Ws0, a1,  lds, wr, wc, lr, lq);
        else if (j == 1) comb_tile(jid, Hv, Ws1, a2,  lds, wr, wc, lr, lq);
        else             comb_tile(jid, Hv, Ws2, a1v, lds, wr, wc, lr, lq);
    } else {
        predict_dev(id - 448, Hv, W0Tv, b0v, W1Tv, b1v, Wfv, bfv,
                    nullptr, g, predv, lds);
    }
}

// ---------------------------------------------------------------------------
// mmB: [0,256) gates_v | [256,320) a2_v | [320,384) predict_c | [384,512) xcvt(t+1)
// ---------------------------------------------------------------------------
__global__ __launch_bounds__(256, 2) void k_mmB(
    const unsigned short* __restrict__ Xh,
    const unsigned short* __restrict__ Hc,
    const unsigned short* __restrict__ WT,
    const float* __restrict__ bias, float* __restrict__ gates,
    const unsigned short* __restrict__ Ws3, float* __restrict__ a2v,
    const unsigned short* __restrict__ W0Tc, const float* __restrict__ b0c,
    const unsigned short* __restrict__ W1Tc, const float* __restrict__ b1c,
    const float* __restrict__ Wfc, const float* __restrict__ bfc,
    float* __restrict__ g, float* __restrict__ predc,
    const float* __restrict__ xnext, unsigned short* __restrict__ Xnh)
{
    __shared__ __align__(16) char lds[65536];
    const int tid = threadIdx.x;
    const int lane = tid & 63, wid = tid >> 6;
    const int wr = wid >> 1, wc = wid & 1;
    const int lr = lane & 15, lq = lane >> 4;
    const int id = blockIdx.x;

    if (id < 256){
        gates_tile(id, Xh, Hc, WT, bias, gates, lds, wr, wc, lr, lq);
    } else if (id < 320){
        comb_tile(id - 256, Hc, Ws3, a2v, lds, wr, wc, lr, lq);
    } else if (id < 384){
        predict_dev(id - 320, Hc, W0Tc, b0c, W1Tc, b1c, Wfc, bfc,
                    g, nullptr, predc, lds);
    } else {
        xcvt_dev(id - 384, xnext, Xnh);
    }
}

// ---------------------------------------------------------------------------
// Cell elementwise update: 1024 blocks x 256 thr x 4 elems.
// mode 0 (click): s=tanh((1-g)a1+g*a2)+i*q+(1-g)*f*s; H=o*tanh(s)
// mode 1 (conv):  s=tanh(a1+g*a2)+(1-g)*s+g*(f*s+i*q); H=(1-g)*Hv32+g*o*tanh(s)
// ---------------------------------------------------------------------------
__global__ __launch_bounds__(256) void k_cell(
    const int mode, const float* __restrict__ gates, const float* __restrict__ a1,
    const float* __restrict__ a2, const float* __restrict__ g,
    float* __restrict__ sstate, float* __restrict__ Hv32,
    unsigned short* __restrict__ Outh)
{
    const size_t BH = (size_t)BATCH * H_DIM;
    const int i4 = blockIdx.x*256 + threadIdx.x;
    const size_t base = (size_t)i4 * 4;
    const int row = (int)(base >> 9);
    const float gv = g[row];
    union U4 { float4 v; float s[4]; };
    U4 f_, i_, o_, q_, u1, u2, sv, hv;
    f_.v = *(const float4*)&gates[base];
    i_.v = *(const float4*)&gates[BH + base];
    o_.v = *(const float4*)&gates[2*BH + base];
    q_.v = *(const float4*)&gates[3*BH + base];
    u1.v = *(const float4*)&a1[base];
    u2.v = *(const float4*)&a2[base];
    sv.v = *(const float4*)&sstate[base];
    if (mode == 1) hv.v = *(const float4*)&Hv32[base];
    U4 sn, hnew;
    union { unsigned short u[4]; ushort4 v; } hh;
#pragma unroll
    for (int e = 0; e < 4; ++e){
        float hval, s;
        if (mode == 0){
            const float shat = tanhf((1.0f - gv)*u1.s[e] + gv*u2.s[e]);
            s = shat + i_.s[e]*q_.s[e] + (1.0f - gv)*(f_.s[e]*sv.s[e]);
            hval = o_.s[e] * tanhf(s);
        } else {
            const float shat = tanhf(u1.s[e] + gv*u2.s[e]);
            const float svo = sv.s[e];
            s = shat + (1.0f - gv)*svo + gv*(f_.s[e]*svo + i_.s[e]*q_.s[e]);
            hval = (1.0f - gv)*hv.s[e] + gv*(o_.s[e]*tanhf(s));
            hnew.s[e] = hval;
        }
        sn.s[e] = s;
        hh.u[e] = f2h(hval);
    }
    *(float4*)&sstate[base] = sn.v;
    if (mode == 1) *(float4*)&Hv32[base] = hnew.v;
    *(ushort4*)&Outh[base] = hh.v;
}

// ---------------------------------------------------------------------------
// Standalone predict (init g0 / final pred_v) and x0 convert.
// ---------------------------------------------------------------------------
__global__ __launch_bounds__(256) void k_predict_g(
    const unsigned short* __restrict__ Hh,
    const unsigned short* __restrict__ W0T, const float* __restrict__ b0,
    const unsigned short* __restrict__ W1T, const float* __restrict__ b1,
    const float* __restrict__ Wf, const float* __restrict__ bf_,
    float* gstate, const float* __restrict__ gmul, float* pred)
{
    __shared__ __align__(16) char lds[53760];
    predict_dev(blockIdx.x, Hh, W0T, b0, W1T, b1, Wf, bf_, gstate, gmul, pred, lds);
}

__global__ __launch_bounds__(256) void k_xcvt_g(const float* __restrict__ x,
                                                unsigned short* __restrict__ oh)
{
    xcvt_dev(blockIdx.x, x, oh);
}

// ---------------------------------------------------------------------------
// Prep kernels (fp16 single)
// ---------------------------------------------------------------------------
__global__ __launch_bounds__(256) void k_wcat(const float* __restrict__ Wx,
                                              const float* __restrict__ Wh,
                                              unsigned short* __restrict__ oh){
    const int n = blockIdx.y;
    const int k = blockIdx.x*256 + threadIdx.x;
    const int z = n >> 9, h = n & 511;
    float v = (k < 256) ? Wx[((size_t)z*E_DIM + k)*H_DIM + h]
                        : Wh[((size_t)z*H_DIM + (k - 256))*H_DIM + h];
    oh[(size_t)n*768 + k] = f2h(v);
}

__global__ __launch_bounds__(256) void k_trans(const float* __restrict__ in,
                                               unsigned short* __restrict__ oh,
                                               int K, int N){
    const int k = blockIdx.x*256 + threadIdx.x;
    const int n = blockIdx.y;
    if (k < K) oh[(size_t)n*K + k] = f2h(in[(size_t)k*N + n]);
}

__global__ __launch_bounds__(256) void k_init(float* __restrict__ sc, float* __restrict__ sv,
                                              float* __restrict__ hv32,
                                              unsigned short* __restrict__ hc0,
                                              unsigned short* __restrict__ hv0){
    const int i = blockIdx.x*256 + threadIdx.x;
    sc[i] = 0.0f; sv[i] = 0.0f; hv32[i] = 0.0f;
    hc0[i] = 0; hv0[i] = 0;
}

// ---------------------------------------------------------------------------
extern "C" void kernel_launch(void* const* d_in, const int* in_sizes, int n_in,
                              void* d_out, int out_size, void* d_ws, size_t ws_size,
                              hipStream_t stream)
{
    (void)in_sizes; (void)n_in; (void)out_size; (void)ws_size;

    const float* inputs = (const float*)d_in[0];
    const float* Wx_c   = (const float*)d_in[1];
    const float* bx_c   = (const float*)d_in[2];
    const float* Wh_c   = (const float*)d_in[3];
    const float* Wx_v   = (const float*)d_in[4];
    const float* bx_v   = (const float*)d_in[5];
    const float* Wh_v   = (const float*)d_in[6];
    const float* Ws     = (const float*)d_in[7];
    const float* Wpc0   = (const float*)d_in[8];
    const float* bpc0   = (const float*)d_in[9];
    const float* Wpc1   = (const float*)d_in[10];
    const float* bpc1   = (const float*)d_in[11];
    const float* Wfcc   = (const float*)d_in[12];
    const float* bfcc   = (const float*)d_in[13];
    const float* Wpv0   = (const float*)d_in[14];
    const float* bpv0   = (const float*)d_in[15];
    const float* Wpv1   = (const float*)d_in[16];
    const float* bpv1   = (const float*)d_in[17];
    const float* Wfcv   = (const float*)d_in[18];
    const float* bfcv   = (const float*)d_in[19];
    float* out = (float*)d_out;

    char* ws = (char*)d_ws;
    size_t off = 0;
    auto allocB = [&](size_t bytes) -> char* {
        char* p = ws + off;
        off = (off + bytes + 255) & ~(size_t)255;
        return p;
    };
    const size_t BH = (size_t)BATCH * H_DIM;
    const size_t BE = (size_t)BATCH * E_DIM;

    unsigned short* Xh[2];
    Xh[0] = (unsigned short*)allocB(BE*2);
    Xh[1] = (unsigned short*)allocB(BE*2);
    unsigned short* WcTc  = (unsigned short*)allocB((size_t)2048*768*2);
    unsigned short* WcTv  = (unsigned short*)allocB((size_t)2048*768*2);
    unsigned short* WsT   = (unsigned short*)allocB((size_t)4*H_DIM*H_DIM*2);
    unsigned short* Wp0Tc = (unsigned short*)allocB((size_t)P0_DIM*H_DIM*2);
    unsigned short* Wp0Tv = (unsigned short*)allocB((size_t)P0_DIM*H_DIM*2);
    unsigned short* Wp1Tc = (unsigned short*)allocB((size_t)P1_DIM*P0_DIM*2);
    unsigned short* Wp1Tv = (unsigned short*)allocB((size_t)P1_DIM*P0_DIM*2);
    unsigned short* Hc    = (unsigned short*)allocB(BH*2);
    unsigned short* Hv    = (unsigned short*)allocB(BH*2);
    float* sc    = (float*)allocB(BH*4);
    float* sv    = (float*)allocB(BH*4);
    float* hv32  = (float*)allocB(BH*4);
    float* gates = (float*)allocB(4*BH*4);
    float* a1    = (float*)allocB(BH*4);
    float* a2    = (float*)allocB(BH*4);
    float* a1v   = (float*)allocB(BH*4);
    float* a2v   = (float*)allocB(BH*4);
    float* g     = (float*)allocB(BATCH*4);

    const dim3 thr(256);
    const size_t HH = (size_t)H_DIM * H_DIM;

    // ---- one-time weight conversion ----
    k_wcat<<<dim3(3, 2048), thr, 0, stream>>>(Wx_c, Wh_c, WcTc);
    k_wcat<<<dim3(3, 2048), thr, 0, stream>>>(Wx_v, Wh_v, WcTv);
    for (int i = 0; i < 4; ++i)
        k_trans<<<dim3(2, 512), thr, 0, stream>>>(Ws + i*HH, WsT + i*HH, H_DIM, H_DIM);
    k_trans<<<dim3(2, 256), thr, 0, stream>>>(Wpc0, Wp0Tc, H_DIM, P0_DIM);
    k_trans<<<dim3(2, 256), thr, 0, stream>>>(Wpv0, Wp0Tv, H_DIM, P0_DIM);
    k_trans<<<dim3(1, 128), thr, 0, stream>>>(Wpc1, Wp1Tc, P0_DIM, P1_DIM);
    k_trans<<<dim3(1, 128), thr, 0, stream>>>(Wpv1, Wp1Tv, P0_DIM, P1_DIM);

    // ---- init: zero states; g0 = predict_c(zeros); convert x(0) ----
    k_init<<<4096, thr, 0, stream>>>(sc, sv, hv32, Hc, Hv);
    k_predict_g<<<64, thr, 0, stream>>>(Hc, Wp0Tc, bpc0, Wp1Tc, bpc1, Wfcc, bfcc,
                                        g, nullptr, nullptr);
    k_xcvt_g<<<128, thr, 0, stream>>>(inputs, Xh[0]);

    for (int t = 0; t < T_STEPS; ++t){
        const int xs = t & 1, xn = xs ^ 1;

        // mmA: gates_c + a1_c + a2_c + a1_v (+ predict_v(t-1) when t>0)
        const int gridA = (t > 0) ? 512 : 448;
        k_mmA<<<gridA, thr, 0, stream>>>(Xh[xs], Hc, Hv,
                                         WcTc, bx_c, gates,
                                         WsT + 0*HH, a1,
                                         WsT + 1*HH, a2,
                                         WsT + 2*HH, a1v,
                                         Wp0Tv, bpv0, Wp1Tv, bpv1, Wfcv, bfcv,
                                         g, out + (size_t)(T_STEPS + t - 1)*BATCH);
        // cell_c -> Hc_new, sc
        k_cell<<<1024, thr, 0, stream>>>(0, gates, a1, a2, g, sc, nullptr, Hc);

        // mmB: gates_v(Hc_new) + a2_v + predict_c (+ xcvt(t+1))
        const int gridB = (t + 1 < T_STEPS) ? 512 : 384;
        k_mmB<<<gridB, thr, 0, stream>>>(Xh[xs], Hc,
                                         WcTv, bx_v, gates,
                                         WsT + 3*HH, a2v,
                                         Wp0Tc, bpc0, Wp1Tc, bpc1, Wfcc, bfcc,
                                         g, out + (size_t)t*BATCH,
                                         inputs + (size_t)(t+1)*BE, Xh[xn]);
        // cell_v -> Hv_new, sv, hv32
        k_cell<<<1024, thr, 0, stream>>>(1, gates, a1v, a2v, g, sv, hv32, Hv);
    }
    // final pred_v(T-1)
    k_predict_g<<<64, thr, 0, stream>>>(Hv, Wp0Tv, bpv0, Wp1Tv, bpv1, Wfcv, bfcv,
                                        nullptr, g, out + (size_t)(2*T_STEPS - 1)*BATCH);
}

// Round 7
// 11976.543 us; speedup vs baseline: 7.0416x; 1.0157x over previous
//
#include <hip/hip_runtime.h>
#include <cstdint>
#include <cstddef>

constexpr int T_STEPS = 200;
constexpr int BATCH   = 2048;
constexpr int E_DIM   = 256;
constexpr int H_DIM   = 512;
constexpr int P0_DIM  = 256;
constexpr int P1_DIM  = 128;
constexpr float ALPHA = 0.3f;

typedef __attribute__((ext_vector_type(8))) _Float16 f16x8;
typedef __attribute__((ext_vector_type(4))) float f32x4;

__device__ __forceinline__ float sigmoidf_(float x){ return 1.0f/(1.0f+expf(-x)); }

__device__ __forceinline__ unsigned short f2h(float f){
    union { _Float16 h; unsigned short u; } v;
    v.h = (_Float16)f;                 // v_cvt_f16_f32, RNE
    return v.u;
}

#define GLOAD16(gp, lp) __builtin_amdgcn_global_load_lds( \
    (const __attribute__((address_space(1))) unsigned int*)(gp), \
    (__attribute__((address_space(3))) unsigned int*)(lp), 16, 0, 0)

// Stage a [ROWS][64] 16-bit tile into linear LDS, slot-swizzled at the SOURCE
// (m173 pattern): LDS[r][s] holds global k-slot (s ^ (r&7)) of row r.
template<int ROWS>
__device__ __forceinline__ void stage64(const unsigned short* __restrict__ src, int ldk,
                                        char* ldsbase){
    constexpr int TOT = ROWS * 8;          // 16B slots
    const int tid = threadIdx.x;
#pragma unroll
    for (int i = 0; i < TOT/256; ++i){
        const int gsl = i*256 + tid;
        const int r = gsl >> 3, s = gsl & 7;
        const int ksrc = ((s ^ (r & 7)) << 3);
        GLOAD16(src + (size_t)r*ldk + ksrc, ldsbase + gsl*16);
    }
}

// Swizzled b128 fragment read: row-stride 128B (BK=64), kslot in [0,8).
__device__ __forceinline__ f16x8 ldsfragh(const char* ldsbase, int row, int kslot){
    return *(const f16x8*)(ldsbase + row*128 + ((kslot ^ (row & 7)) << 4));
}

// ---------------------------------------------------------------------------
// 128x128-tile fp16 K-loop, double-buffered with COUNTED vmcnt (T4):
//   prologue: stage buf0 (8 loads/wave outstanding)
//   per slab: [stage next into buf^1 (+8)] -> vmcnt(8|0) + raw s_barrier
//             -> setprio(1) ds_read+MFMA setprio(0) -> raw s_barrier
// Next-slab loads stay in flight across the MFMA phase (never drained to 0
// except on the last slab). Trailing barrier protects buffer reuse.
// LDS: buf b at lds + b*32768 (A at +0, B at +16384). 64 KB total.
// ---------------------------------------------------------------------------
__device__ __forceinline__ void mm_loop128h(
    const unsigned short* __restrict__ A, int lda,
    const unsigned short* __restrict__ B, int ldb,
    int K, f32x4 (&acc)[4][4], char* lds, int wr, int wc, int lr, int lq)
{
    stage64<128>(A, lda, lds);
    stage64<128>(B, ldb, lds + 16384);
    int cur = 0;
    for (int k0 = 0; k0 < K; k0 += 64){
        char* bufc = lds + cur*32768;
        if (k0 + 64 < K){
            char* bufn = lds + (cur^1)*32768;
            stage64<128>(A + k0 + 64, lda, bufn);
            stage64<128>(B + k0 + 64, ldb, bufn + 16384);
            asm volatile("s_waitcnt vmcnt(8)" ::: "memory");   // current slab landed
        } else {
            asm volatile("s_waitcnt vmcnt(0)" ::: "memory");   // last slab: drain
        }
        __builtin_amdgcn_s_barrier();          // raw barrier: no vmcnt(0) drain
        __builtin_amdgcn_sched_barrier(0);     // pin: no ds_read hoist above barrier
        __builtin_amdgcn_s_setprio(1);
#pragma unroll
        for (int kk = 0; kk < 2; ++kk){
            f16x8 a[4], b[4];
#pragma unroll
            for (int m = 0; m < 4; ++m) a[m] = ldsfragh(bufc, wr*64 + m*16 + lr, kk*4 + lq);
#pragma unroll
            for (int n = 0; n < 4; ++n) b[n] = ldsfragh(bufc + 16384, wc*64 + n*16 + lr, kk*4 + lq);
#pragma unroll
            for (int m = 0; m < 4; ++m)
#pragma unroll
                for (int n = 0; n < 4; ++n)
                    acc[m][n] = __builtin_amdgcn_mfma_f32_16x16x32_f16(a[m], b[n], acc[m][n], 0,0,0);
        }
        __builtin_amdgcn_s_setprio(0);
        __builtin_amdgcn_sched_barrier(0);     // pin: reads complete before barrier
        __builtin_amdgcn_s_barrier();          // all waves done reading bufc
        cur ^= 1;
    }
}

// ---------------------------------------------------------------------------
// Gates tile (id in [0,256), XCD-swizzled): gates = act(x@Wx + H@Wh + bias)
// ---------------------------------------------------------------------------
__device__ __forceinline__ void gates_tile(
    int id,
    const unsigned short* __restrict__ Xh,
    const unsigned short* __restrict__ Hh,
    const unsigned short* __restrict__ WT,
    const float* __restrict__ bias, float* __restrict__ gates,
    char* lds, int wr, int wc, int lr, int lq)
{
    // XCD-bijective swizzle: XCD k gets sw in [k*32,(k+1)*32) = 2 B-panels x 16 row-tiles
    const int sw = ((id & 7) << 5) + (id >> 3);
    const int brow = (sw & 15) * 128;         // col-major tile order
    const int bcol = (sw >> 4) * 128;

    f32x4 acc[4][4];
#pragma unroll
    for (int m = 0; m < 4; ++m)
#pragma unroll
        for (int n = 0; n < 4; ++n){ f32x4 z = {0.f,0.f,0.f,0.f}; acc[m][n] = z; }

    mm_loop128h(Xh + (size_t)brow*E_DIM, E_DIM,
                WT + (size_t)bcol*768, 768,
                E_DIM, acc, lds, wr, wc, lr, lq);
    mm_loop128h(Hh + (size_t)brow*H_DIM, H_DIM,
                WT + (size_t)bcol*768 + E_DIM, 768,
                H_DIM, acc, lds, wr, wc, lr, lq);

    const int z = bcol >> 9;
    const int hbase = (bcol & 511) + wc*64;
    float* gz = gates + (size_t)z * BATCH * H_DIM;
#pragma unroll
    for (int m = 0; m < 4; ++m){
#pragma unroll
        for (int n = 0; n < 4; ++n){
            const int h = hbase + n*16 + lr;
            const float bs = bias[z*H_DIM + h];
#pragma unroll
            for (int r = 0; r < 4; ++r){
                const int b2 = brow + wr*64 + m*16 + lq*4 + r;
                float v = acc[m][n][r] + bs;
                v = (z < 3) ? sigmoidf_(v) : tanhf(v);
                gz[(size_t)b2 * H_DIM + h] = v;
            }
        }
    }
}

// ---------------------------------------------------------------------------
// Comb tile (jid in [0,64)): out = A @ B^T raw fp32 (M=2048,N=512,K=512)
// ---------------------------------------------------------------------------
__device__ __forceinline__ void comb_tile(
    int jid,
    const unsigned short* __restrict__ A,
    const unsigned short* __restrict__ B,
    float* __restrict__ outp, char* lds, int wr, int wc, int lr, int lq)
{
    const int brow = (jid >> 2) * 128, bcol = (jid & 3) * 128;
    f32x4 acc[4][4];
#pragma unroll
    for (int m = 0; m < 4; ++m)
#pragma unroll
        for (int n = 0; n < 4; ++n){ f32x4 z = {0.f,0.f,0.f,0.f}; acc[m][n] = z; }

    mm_loop128h(A + (size_t)brow*H_DIM, H_DIM,
                B + (size_t)bcol*H_DIM, H_DIM,
                H_DIM, acc, lds, wr, wc, lr, lq);
#pragma unroll
    for (int m = 0; m < 4; ++m){
#pragma unroll
        for (int n = 0; n < 4; ++n){
            const int h = bcol + wc*64 + n*16 + lr;
#pragma unroll
            for (int r = 0; r < 4; ++r){
                const int b2 = brow + wr*64 + m*16 + lq*4 + r;
                outp[(size_t)b2 * H_DIM + h] = acc[m][n][r];
            }
        }
    }
}

// ---------------------------------------------------------------------------
// Predict (32 rows per pblk): p0=leaky(H@W0+b0), p1=leaky(p0@W1+b1),
// val=sigmoid(dot(p1,Wf)+bf) (*gmul). fp16 operands, fp32 accum.
// ---------------------------------------------------------------------------
__device__ __forceinline__ void predict_dev(
    int pblk, const unsigned short* __restrict__ Hh,
    const unsigned short* __restrict__ W0T, const float* __restrict__ b0,
    const unsigned short* __restrict__ W1T, const float* __restrict__ b1,
    const float* __restrict__ Wf, const float* __restrict__ bf_,
    float* gstate, const float* __restrict__ gmul, float* pred, char* lds)
{
    char*  ldsA = lds;                    // [32][128B]
    char*  ldsB = lds + 4096;             // up to [256][128B]
    char*  ldsP = lds + 36864;            // [32][512B] p0 fp16 (swizzled)
    float* sums = (float*)(lds + 53248);  // [4][32]
    const int tid = threadIdx.x, lane = tid & 63, w = tid >> 6;
    const int lr = lane & 15, lq = lane >> 4;
    const int brow = pblk * 32;

    f32x4 acc0[2][4];
#pragma unroll
    for (int m = 0; m < 2; ++m)
#pragma unroll
        for (int n = 0; n < 4; ++n){ f32x4 z = {0.f,0.f,0.f,0.f}; acc0[m][n] = z; }

    for (int k0 = 0; k0 < H_DIM; k0 += 64){
        stage64<32>(Hh + (size_t)brow*H_DIM + k0, H_DIM, ldsA);
        stage64<256>(W0T + k0, H_DIM, ldsB);
        __syncthreads();
#pragma unroll
        for (int kk = 0; kk < 2; ++kk){
            f16x8 a[2], b[4];
#pragma unroll
            for (int m = 0; m < 2; ++m) a[m] = ldsfragh(ldsA, m*16 + lr, kk*4 + lq);
#pragma unroll
            for (int n = 0; n < 4; ++n) b[n] = ldsfragh(ldsB, w*64 + n*16 + lr, kk*4 + lq);
#pragma unroll
            for (int m = 0; m < 2; ++m)
#pragma unroll
                for (int n = 0; n < 4; ++n)
                    acc0[m][n] = __builtin_amdgcn_mfma_f32_16x16x32_f16(a[m], b[n], acc0[m][n], 0,0,0);
        }
        __syncthreads();
    }
#pragma unroll
    for (int m = 0; m < 2; ++m){
#pragma unroll
        for (int n = 0; n < 4; ++n){
            const int col = w*64 + n*16 + lr;
            const float bs = b0[col];
#pragma unroll
            for (int r = 0; r < 4; ++r){
                const int row = m*16 + lq*4 + r;
                float x = acc0[m][n][r] + bs;
                x = (x > 0.0f) ? x : ALPHA*x;
                *(unsigned short*)(ldsP + row*512 + ((((col >> 3)) ^ (row & 7)) << 4) + (col & 7)*2) = f2h(x);
            }
        }
    }
    __syncthreads();

    f32x4 accp[2][2];
#pragma unroll
    for (int m = 0; m < 2; ++m)
#pragma unroll
        for (int n = 0; n < 2; ++n){ f32x4 z = {0.f,0.f,0.f,0.f}; accp[m][n] = z; }

    for (int k0 = 0; k0 < P0_DIM; k0 += 64){
        stage64<128>(W1T + k0, P0_DIM, ldsB);
        __syncthreads();
#pragma unroll
        for (int kk = 0; kk < 2; ++kk){
            f16x8 a[2], b[2];
#pragma unroll
            for (int m = 0; m < 2; ++m){
                const int row = m*16 + lr;
                const int slot = (k0 >> 3) + kk*4 + lq;
                a[m] = *(const f16x8*)(ldsP + row*512 + ((slot ^ (row & 7)) << 4));
            }
#pragma unroll
            for (int n = 0; n < 2; ++n) b[n] = ldsfragh(ldsB, w*32 + n*16 + lr, kk*4 + lq);
#pragma unroll
            for (int m = 0; m < 2; ++m)
#pragma unroll
                for (int n = 0; n < 2; ++n)
                    accp[m][n] = __builtin_amdgcn_mfma_f32_16x16x32_f16(a[m], b[n], accp[m][n], 0,0,0);
        }
        __syncthreads();
    }

    float part[8];
#pragma unroll
    for (int j = 0; j < 8; ++j) part[j] = 0.0f;
#pragma unroll
    for (int m = 0; m < 2; ++m){
#pragma unroll
        for (int n = 0; n < 2; ++n){
            const int col = w*32 + n*16 + lr;
            const float bs = b1[col], wf = Wf[col];
#pragma unroll
            for (int r = 0; r < 4; ++r){
                float x = accp[m][n][r] + bs;
                x = (x > 0.0f) ? x : ALPHA*x;
                part[m*4 + r] += x * wf;
            }
        }
    }
#pragma unroll
    for (int mask = 1; mask < 16; mask <<= 1)
#pragma unroll
        for (int j = 0; j < 8; ++j) part[j] += __shfl_xor(part[j], mask);
    if (lr == 0){
#pragma unroll
        for (int j = 0; j < 8; ++j){
            const int row = (j >> 2)*16 + lq*4 + (j & 3);
            sums[w*32 + row] = part[j];
        }
    }
    __syncthreads();
    if (tid < 32){
        float tot = sums[tid] + sums[32 + tid] + sums[64 + tid] + sums[96 + tid] + bf_[0];
        float val = sigmoidf_(tot);
        const int rowg = brow + tid;
        if (gmul)   val *= gmul[rowg];
        if (gstate) gstate[rowg] = val;
        if (pred)   pred[rowg]   = val;
    }
}

// x-step fp16 convert: 128 blocks x 256 thr x 4 float4.
__device__ __forceinline__ void xcvt_dev(int blk, const float* __restrict__ x,
                                         unsigned short* __restrict__ oh)
{
    const int tid = threadIdx.x;
#pragma unroll
    for (int j = 0; j < 4; ++j){
        const int t = blk*256 + tid + j*32768;
        float4 v = ((const float4*)x)[t];
        ushort4 h;
        h.x = f2h(v.x); h.y = f2h(v.y); h.z = f2h(v.z); h.w = f2h(v.w);
        ((ushort4*)oh)[t] = h;
    }
}

// ---------------------------------------------------------------------------
// mmA: [0,256) gates_c | [256,448) comb a1_c/a2_c/a1_v | [448,512) predict_v(t-1)
// ---------------------------------------------------------------------------
__global__ __launch_bounds__(256, 2) void k_mmA(
    const unsigned short* __restrict__ Xh,
    const unsigned short* __restrict__ Hc, const unsigned short* __restrict__ Hv,
    const unsigned short* __restrict__ WT,
    const float* __restrict__ bias, float* __restrict__ gates,
    const unsigned short* __restrict__ Ws0, float* __restrict__ a1,
    const unsigned short* __restrict__ Ws1, float* __restrict__ a2,
    const unsigned short* __restrict__ Ws2, float* __restrict__ a1v,
    const unsigned short* __restrict__ W0Tv, const float* __restrict__ b0v,
    const unsigned short* __restrict__ W1Tv, const float* __restrict__ b1v,
    const float* __restrict__ Wfv, const float* __restrict__ bfv,
    const float* __restrict__ g, float* __restrict__ predv)
{
    __shared__ __align__(16) char lds[65536];
    const int tid = threadIdx.x;
    const int lane = tid & 63, wid = tid >> 6;
    const int wr = wid >> 1, wc = wid & 1;
    const int lr = lane & 15, lq = lane >> 4;
    const int id = blockIdx.x;

    if (id < 256){
        gates_tile(id, Xh, Hc, WT, bias, gates, lds, wr, wc, lr, lq);
    } else if (id < 448){
        const int j = (id - 256) >> 6, jid = (id - 256) & 63;
        if (j == 0)      comb_tile(jid, Hc, Ws0, a1,  lds, wr, wc, lr, lq);
        else if (j == 1) comb_tile(jid, Hv, Ws1, a2,  lds, wr, wc, lr, lq);
        else             comb_tile(jid, Hv, Ws2, a1v, lds, wr, wc, lr, lq);
    } else {
        predict_dev(id - 448, Hv, W0Tv, b0v, W1Tv, b1v, Wfv, bfv,
                    nullptr, g, predv, lds);
    }
}

// ---------------------------------------------------------------------------
// mmB: [0,256) gates_v | [256,320) a2_v | [320,384) predict_c | [384,512) xcvt(t+1)
// ---------------------------------------------------------------------------
__global__ __launch_bounds__(256, 2) void k_mmB(
    const unsigned short* __restrict__ Xh,
    const unsigned short* __restrict__ Hc,
    const unsigned short* __restrict__ WT,
    const float* __restrict__ bias, float* __restrict__ gates,
    const unsigned short* __restrict__ Ws3, float* __restrict__ a2v,
    const unsigned short* __restrict__ W0Tc, const float* __restrict__ b0c,
    const unsigned short* __restrict__ W1Tc, const float* __restrict__ b1c,
    const float* __restrict__ Wfc, const float* __restrict__ bfc,
    float* __restrict__ g, float* __restrict__ predc,
    const float* __restrict__ xnext, unsigned short* __restrict__ Xnh)
{
    __shared__ __align__(16) char lds[65536];
    const int tid = threadIdx.x;
    const int lane = tid & 63, wid = tid >> 6;
    const int wr = wid >> 1, wc = wid & 1;
    const int lr = lane & 15, lq = lane >> 4;
    const int id = blockIdx.x;

    if (id < 256){
        gates_tile(id, Xh, Hc, WT, bias, gates, lds, wr, wc, lr, lq);
    } else if (id < 320){
        comb_tile(id - 256, Hc, Ws3, a2v, lds, wr, wc, lr, lq);
    } else if (id < 384){
        predict_dev(id - 320, Hc, W0Tc, b0c, W1Tc, b1c, Wfc, bfc,
                    g, nullptr, predc, lds);
    } else {
        xcvt_dev(id - 384, xnext, Xnh);
    }
}

// ---------------------------------------------------------------------------
// Cell elementwise update: 1024 blocks x 256 thr x 4 elems.
// mode 0 (click): s=tanh((1-g)a1+g*a2)+i*q+(1-g)*f*s; H=o*tanh(s)
// mode 1 (conv):  s=tanh(a1+g*a2)+(1-g)*s+g*(f*s+i*q); H=(1-g)*Hv32+g*o*tanh(s)
// ---------------------------------------------------------------------------
__global__ __launch_bounds__(256) void k_cell(
    const int mode, const float* __restrict__ gates, const float* __restrict__ a1,
    const float* __restrict__ a2, const float* __restrict__ g,
    float* __restrict__ sstate, float* __restrict__ Hv32,
    unsigned short* __restrict__ Outh)
{
    const size_t BH = (size_t)BATCH * H_DIM;
    const int i4 = blockIdx.x*256 + threadIdx.x;
    const size_t base = (size_t)i4 * 4;
    const int row = (int)(base >> 9);
    const float gv = g[row];
    union U4 { float4 v; float s[4]; };
    U4 f_, i_, o_, q_, u1, u2, sv, hv;
    f_.v = *(const float4*)&gates[base];
    i_.v = *(const float4*)&gates[BH + base];
    o_.v = *(const float4*)&gates[2*BH + base];
    q_.v = *(const float4*)&gates[3*BH + base];
    u1.v = *(const float4*)&a1[base];
    u2.v = *(const float4*)&a2[base];
    sv.v = *(const float4*)&sstate[base];
    if (mode == 1) hv.v = *(const float4*)&Hv32[base];
    U4 sn, hnew;
    union { unsigned short u[4]; ushort4 v; } hh;
#pragma unroll
    for (int e = 0; e < 4; ++e){
        float hval, s;
        if (mode == 0){
            const float shat = tanhf((1.0f - gv)*u1.s[e] + gv*u2.s[e]);
            s = shat + i_.s[e]*q_.s[e] + (1.0f - gv)*(f_.s[e]*sv.s[e]);
            hval = o_.s[e] * tanhf(s);
        } else {
            const float shat = tanhf(u1.s[e] + gv*u2.s[e]);
            const float svo = sv.s[e];
            s = shat + (1.0f - gv)*svo + gv*(f_.s[e]*svo + i_.s[e]*q_.s[e]);
            hval = (1.0f - gv)*hv.s[e] + gv*(o_.s[e]*tanhf(s));
            hnew.s[e] = hval;
        }
        sn.s[e] = s;
        hh.u[e] = f2h(hval);
    }
    *(float4*)&sstate[base] = sn.v;
    if (mode == 1) *(float4*)&Hv32[base] = hnew.v;
    *(ushort4*)&Outh[base] = hh.v;
}

// ---------------------------------------------------------------------------
// Standalone predict (init g0 / final pred_v) and x0 convert.
// ---------------------------------------------------------------------------
__global__ __launch_bounds__(256) void k_predict_g(
    const unsigned short* __restrict__ Hh,
    const unsigned short* __restrict__ W0T, const float* __restrict__ b0,
    const unsigned short* __restrict__ W1T, const float* __restrict__ b1,
    const float* __restrict__ Wf, const float* __restrict__ bf_,
    float* gstate, const float* __restrict__ gmul, float* pred)
{
    __shared__ __align__(16) char lds[53760];
    predict_dev(blockIdx.x, Hh, W0T, b0, W1T, b1, Wf, bf_, gstate, gmul, pred, lds);
}

__global__ __launch_bounds__(256) void k_xcvt_g(const float* __restrict__ x,
                                                unsigned short* __restrict__ oh)
{
    xcvt_dev(blockIdx.x, x, oh);
}

// ---------------------------------------------------------------------------
// Prep kernels (fp16 single)
// ---------------------------------------------------------------------------
__global__ __launch_bounds__(256) void k_wcat(const float* __restrict__ Wx,
                                              const float* __restrict__ Wh,
                                              unsigned short* __restrict__ oh){
    const int n = blockIdx.y;
    const int k = blockIdx.x*256 + threadIdx.x;
    const int z = n >> 9, h = n & 511;
    float v = (k < 256) ? Wx[((size_t)z*E_DIM + k)*H_DIM + h]
                        : Wh[((size_t)z*H_DIM + (k - 256))*H_DIM + h];
    oh[(size_t)n*768 + k] = f2h(v);
}

__global__ __launch_bounds__(256) void k_trans(const float* __restrict__ in,
                                               unsigned short* __restrict__ oh,
                                               int K, int N){
    const int k = blockIdx.x*256 + threadIdx.x;
    const int n = blockIdx.y;
    if (k < K) oh[(size_t)n*K + k] = f2h(in[(size_t)k*N + n]);
}

__global__ __launch_bounds__(256) void k_init(float* __restrict__ sc, float* __restrict__ sv,
                                              float* __restrict__ hv32,
                                              unsigned short* __restrict__ hc0,
                                              unsigned short* __restrict__ hv0){
    const int i = blockIdx.x*256 + threadIdx.x;
    sc[i] = 0.0f; sv[i] = 0.0f; hv32[i] = 0.0f;
    hc0[i] = 0; hv0[i] = 0;
}

// ---------------------------------------------------------------------------
extern "C" void kernel_launch(void* const* d_in, const int* in_sizes, int n_in,
                              void* d_out, int out_size, void* d_ws, size_t ws_size,
                              hipStream_t stream)
{
    (void)in_sizes; (void)n_in; (void)out_size; (void)ws_size;

    const float* inputs = (const float*)d_in[0];
    const float* Wx_c   = (const float*)d_in[1];
    const float* bx_c   = (const float*)d_in[2];
    const float* Wh_c   = (const float*)d_in[3];
    const float* Wx_v   = (const float*)d_in[4];
    const float* bx_v   = (const float*)d_in[5];
    const float* Wh_v   = (const float*)d_in[6];
    const float* Ws     = (const float*)d_in[7];
    const float* Wpc0   = (const float*)d_in[8];
    const float* bpc0   = (const float*)d_in[9];
    const float* Wpc1   = (const float*)d_in[10];
    const float* bpc1   = (const float*)d_in[11];
    const float* Wfcc   = (const float*)d_in[12];
    const float* bfcc   = (const float*)d_in[13];
    const float* Wpv0   = (const float*)d_in[14];
    const float* bpv0   = (const float*)d_in[15];
    const float* Wpv1   = (const float*)d_in[16];
    const float* bpv1   = (const float*)d_in[17];
    const float* Wfcv   = (const float*)d_in[18];
    const float* bfcv   = (const float*)d_in[19];
    float* out = (float*)d_out;

    char* ws = (char*)d_ws;
    size_t off = 0;
    auto allocB = [&](size_t bytes) -> char* {
        char* p = ws + off;
        off = (off + bytes + 255) & ~(size_t)255;
        return p;
    };
    const size_t BH = (size_t)BATCH * H_DIM;
    const size_t BE = (size_t)BATCH * E_DIM;

    unsigned short* Xh[2];
    Xh[0] = (unsigned short*)allocB(BE*2);
    Xh[1] = (unsigned short*)allocB(BE*2);
    unsigned short* WcTc  = (unsigned short*)allocB((size_t)2048*768*2);
    unsigned short* WcTv  = (unsigned short*)allocB((size_t)2048*768*2);
    unsigned short* WsT   = (unsigned short*)allocB((size_t)4*H_DIM*H_DIM*2);
    unsigned short* Wp0Tc = (unsigned short*)allocB((size_t)P0_DIM*H_DIM*2);
    unsigned short* Wp0Tv = (unsigned short*)allocB((size_t)P0_DIM*H_DIM*2);
    unsigned short* Wp1Tc = (unsigned short*)allocB((size_t)P1_DIM*P0_DIM*2);
    unsigned short* Wp1Tv = (unsigned short*)allocB((size_t)P1_DIM*P0_DIM*2);
    unsigned short* Hc    = (unsigned short*)allocB(BH*2);
    unsigned short* Hv    = (unsigned short*)allocB(BH*2);
    float* sc    = (float*)allocB(BH*4);
    float* sv    = (float*)allocB(BH*4);
    float* hv32  = (float*)allocB(BH*4);
    float* gates = (float*)allocB(4*BH*4);
    float* a1    = (float*)allocB(BH*4);
    float* a2    = (float*)allocB(BH*4);
    float* a1v   = (float*)allocB(BH*4);
    float* a2v   = (float*)allocB(BH*4);
    float* g     = (float*)allocB(BATCH*4);

    const dim3 thr(256);
    const size_t HH = (size_t)H_DIM * H_DIM;

    // ---- one-time weight conversion ----
    k_wcat<<<dim3(3, 2048), thr, 0, stream>>>(Wx_c, Wh_c, WcTc);
    k_wcat<<<dim3(3, 2048), thr, 0, stream>>>(Wx_v, Wh_v, WcTv);
    for (int i = 0; i < 4; ++i)
        k_trans<<<dim3(2, 512), thr, 0, stream>>>(Ws + i*HH, WsT + i*HH, H_DIM, H_DIM);
    k_trans<<<dim3(2, 256), thr, 0, stream>>>(Wpc0, Wp0Tc, H_DIM, P0_DIM);
    k_trans<<<dim3(2, 256), thr, 0, stream>>>(Wpv0, Wp0Tv, H_DIM, P0_DIM);
    k_trans<<<dim3(1, 128), thr, 0, stream>>>(Wpc1, Wp1Tc, P0_DIM, P1_DIM);
    k_trans<<<dim3(1, 128), thr, 0, stream>>>(Wpv1, Wp1Tv, P0_DIM, P1_DIM);

    // ---- init: zero states; g0 = predict_c(zeros); convert x(0) ----
    k_init<<<4096, thr, 0, stream>>>(sc, sv, hv32, Hc, Hv);
    k_predict_g<<<64, thr, 0, stream>>>(Hc, Wp0Tc, bpc0, Wp1Tc, bpc1, Wfcc, bfcc,
                                        g, nullptr, nullptr);
    k_xcvt_g<<<128, thr, 0, stream>>>(inputs, Xh[0]);

    for (int t = 0; t < T_STEPS; ++t){
        const int xs = t & 1, xn = xs ^ 1;

        // mmA: gates_c + a1_c + a2_c + a1_v (+ predict_v(t-1) when t>0)
        const int gridA = (t > 0) ? 512 : 448;
        k_mmA<<<gridA, thr, 0, stream>>>(Xh[xs], Hc, Hv,
                                         WcTc, bx_c, gates,
                                         WsT + 0*HH, a1,
                                         WsT + 1*HH, a2,
                                         WsT + 2*HH, a1v,
                                         Wp0Tv, bpv0, Wp1Tv, bpv1, Wfcv, bfcv,
                                         g, out + (size_t)(T_STEPS + t - 1)*BATCH);
        // cell_c -> Hc_new, sc
        k_cell<<<1024, thr, 0, stream>>>(0, gates, a1, a2, g, sc, nullptr, Hc);

        // mmB: gates_v(Hc_new) + a2_v + predict_c (+ xcvt(t+1))
        const int gridB = (t + 1 < T_STEPS) ? 512 : 384;
        k_mmB<<<gridB, thr, 0, stream>>>(Xh[xs], Hc,
                                         WcTv, bx_v, gates,
                                         WsT + 3*HH, a2v,
                                         Wp0Tc, bpc0, Wp1Tc, bpc1, Wfcc, bfcc,
                                         g, out + (size_t)t*BATCH,
                                         inputs + (size_t)(t+1)*BE, Xh[xn]);
        // cell_v -> Hv_new, sv, hv32
        k_cell<<<1024, thr, 0, stream>>>(1, gates, a1v, a2v, g, sv, hv32, Hv);
    }
    // final pred_v(T-1)
    k_predict_g<<<64, thr, 0, stream>>>(Hv, Wp0Tv, bpv0, Wp1Tv, bpv1, Wfcv, bfcv,
                                        nullptr, g, out + (size_t)(2*T_STEPS - 1)*BATCH);
}